// Round 1
// baseline (2850.961 us; speedup 1.0000x reference)
//
#include <hip/hip_runtime.h>
#include <math.h>

#define NB 8
#define CIN 256
#define CR 64
#define H 64
#define W 64
#define HW 4096

static const size_t QKV = (size_t)NB * CR * HW;   // 2,097,152 floats per q/k/v/attu buffer
static const size_t NHW = (size_t)NB * HW;        // 32,768

// ---------------------------------------------------------------- conv K x K
// One block per (n, co). Stage one 64x64 input plane per ci in LDS.
// Each thread computes a 4x4 output tile.
template<int K>
__global__ __launch_bounds__(256) void conv_kernel(
    const float* __restrict__ fm, const float* __restrict__ w,
    const float* __restrict__ b, float* __restrict__ dst)
{
    constexpr int PAD = K / 2;
    const int n  = blockIdx.x / CR;
    const int co = blockIdx.x % CR;
    const int tid = threadIdx.x;
    const int tx = (tid & 15) * 4;
    const int ty = (tid >> 4) * 4;
    __shared__ float plane[HW];

    float acc[16];
#pragma unroll
    for (int t = 0; t < 16; ++t) acc[t] = 0.f;

    const float* fmn = fm + (size_t)n * CIN * HW;
    const float* wco = w + (size_t)co * CIN * K * K;

    for (int ci = 0; ci < CIN; ++ci) {
        __syncthreads();  // protect plane from previous iteration's readers
        {
            const float4* src = (const float4*)(fmn + (size_t)ci * HW);
            float4* dl = (float4*)plane;
#pragma unroll
            for (int t = 0; t < 4; ++t) dl[tid + t * 256] = src[tid + t * 256];
        }
        __syncthreads();

        float wr[K * K];
#pragma unroll
        for (int t = 0; t < K * K; ++t) wr[t] = wco[ci * K * K + t];

#pragma unroll
        for (int ry = 0; ry < K + 3; ++ry) {
            const int iy = ty + ry - PAD;
            const bool yok = (iy >= 0) && (iy < H);
            float rv[K + 3];
#pragma unroll
            for (int t = 0; t < K + 3; ++t) {
                const int ix = tx + t - PAD;
                rv[t] = (yok && ix >= 0 && ix < W) ? plane[iy * W + ix] : 0.f;
            }
#pragma unroll
            for (int dy = 0; dy < K; ++dy) {
                const int oy = ry - dy;
                if (oy < 0 || oy > 3) continue;
#pragma unroll
                for (int dx = 0; dx < K; ++dx) {
                    const float wv = wr[dy * K + dx];
#pragma unroll
                    for (int ox = 0; ox < 4; ++ox)
                        acc[oy * 4 + ox] = fmaf(wv, rv[ox + dx], acc[oy * 4 + ox]);
                }
            }
        }
    }

    const float bias = b[co];
    float* d = dst + (size_t)(n * CR + co) * HW;
#pragma unroll
    for (int oy = 0; oy < 4; ++oy) {
        float4 o;
        o.x = acc[oy * 4 + 0] + bias;
        o.y = acc[oy * 4 + 1] + bias;
        o.z = acc[oy * 4 + 2] + bias;
        o.w = acc[oy * 4 + 3] + bias;
        *(float4*)(d + (ty + oy) * W + tx) = o;
    }
}

// ------------------------------------------------- fused qk + online softmax + PV
// One block per (n, 64-column j-tile). Per-column online softmax (m_j, z_j),
// PV accumulated unnormalized relative to each column's running max.
__global__ __launch_bounds__(256) void attn_kernel(
    const float* __restrict__ q, const float* __restrict__ k, const float* __restrict__ v,
    float* __restrict__ attu, float* __restrict__ Mcol, float* __restrict__ Zcol)
{
    const int n  = blockIdx.x >> 6;
    const int jb = blockIdx.x & 63;
    const int j0 = jb * 64;
    const int tid = threadIdx.x;

    __shared__ float qt[64 * 64];   // [c][j]
    __shared__ float kt[64 * 64];   // [c][i]
    __shared__ float vt[64 * 64];   // [i][c]  (transposed)
    __shared__ float St[64 * 64];   // [i][j]
    __shared__ float mcol[64], zcol[64], rcol[64];
    __shared__ float pm[256], pz[256];

    // load q tile once
    {
        const int c  = tid >> 2;
        const int jj = (tid & 3) * 16;
        const float* src = q + (size_t)(n * CR + c) * HW + j0 + jj;
#pragma unroll
        for (int e = 0; e < 4; ++e)
            *(float4*)&qt[c * 64 + jj + e * 4] = *(const float4*)(src + e * 4);
    }
    if (tid < 64) { mcol[tid] = -1e30f; zcol[tid] = 0.f; }

    float acc[16];
#pragma unroll
    for (int t = 0; t < 16; ++t) acc[t] = 0.f;

    const int ti = tid & 15;      // phase1: i-subtile / phase3: c-subtile
    const int tj = tid >> 4;      // j-subtile (both phases)
    const int jcol = tid & 63;    // phase2 column
    const int qr   = tid >> 6;    // phase2 quarter

    for (int it = 0; it < 64; ++it) {
        const int i0 = it * 64;
        __syncthreads();  // previous iteration's kt/vt/St readers done
        {
            const int c  = tid >> 2;
            const int ii = (tid & 3) * 16;
            const float* ks = k + (size_t)(n * CR + c) * HW + i0 + ii;
            const float* vs = v + (size_t)(n * CR + c) * HW + i0 + ii;
#pragma unroll
            for (int e = 0; e < 4; ++e)
                *(float4*)&kt[c * 64 + ii + e * 4] = *(const float4*)(ks + e * 4);
#pragma unroll
            for (int e = 0; e < 16; ++e)
                vt[(ii + e) * 64 + c] = vs[e];
        }
        __syncthreads();

        // phase 1: S-tile = K^T Q  (rows i, cols j)
        float s[16];
#pragma unroll
        for (int t = 0; t < 16; ++t) s[t] = 0.f;
#pragma unroll 8
        for (int c = 0; c < 64; ++c) {
            const float4 kv = *(const float4*)&kt[c * 64 + ti * 4];
            const float4 qv = *(const float4*)&qt[c * 64 + tj * 4];
            s[0]  = fmaf(kv.x, qv.x, s[0]);  s[1]  = fmaf(kv.x, qv.y, s[1]);
            s[2]  = fmaf(kv.x, qv.z, s[2]);  s[3]  = fmaf(kv.x, qv.w, s[3]);
            s[4]  = fmaf(kv.y, qv.x, s[4]);  s[5]  = fmaf(kv.y, qv.y, s[5]);
            s[6]  = fmaf(kv.y, qv.z, s[6]);  s[7]  = fmaf(kv.y, qv.w, s[7]);
            s[8]  = fmaf(kv.z, qv.x, s[8]);  s[9]  = fmaf(kv.z, qv.y, s[9]);
            s[10] = fmaf(kv.z, qv.z, s[10]); s[11] = fmaf(kv.z, qv.w, s[11]);
            s[12] = fmaf(kv.w, qv.x, s[12]); s[13] = fmaf(kv.w, qv.y, s[13]);
            s[14] = fmaf(kv.w, qv.z, s[14]); s[15] = fmaf(kv.w, qv.w, s[15]);
        }
#pragma unroll
        for (int a = 0; a < 4; ++a) {
            float4 o;
            o.x = s[a * 4 + 0]; o.y = s[a * 4 + 1]; o.z = s[a * 4 + 2]; o.w = s[a * 4 + 3];
            *(float4*)&St[(ti * 4 + a) * 64 + tj * 4] = o;
        }
        __syncthreads();

        // phase 2a: per-column partial max over this tile
        float lm = -1e30f;
#pragma unroll
        for (int t = 0; t < 16; ++t) lm = fmaxf(lm, St[(qr * 16 + t) * 64 + jcol]);
        pm[qr * 64 + jcol] = lm;
        const float mold = mcol[jcol];
        __syncthreads();

        // phase 2b: new running max, exp in place, partial sums
        const float mt = fmaxf(fmaxf(pm[jcol], pm[64 + jcol]),
                               fmaxf(pm[128 + jcol], pm[192 + jcol]));
        const float mnew = fmaxf(mold, mt);
        const float r = __expf(mold - mnew);
        float ps = 0.f;
#pragma unroll
        for (int t = 0; t < 16; ++t) {
            const int idx = (qr * 16 + t) * 64 + jcol;
            const float e = __expf(St[idx] - mnew);
            St[idx] = e;
            ps += e;
        }
        pz[qr * 64 + jcol] = ps;
        __syncthreads();

        // phase 2c: fold into column state
        if (qr == 0) {
            const float zt = pz[jcol] + pz[64 + jcol] + pz[128 + jcol] + pz[192 + jcol];
            zcol[jcol] = zcol[jcol] * r + zt;
            mcol[jcol] = mnew;
            rcol[jcol] = r;
        }
        __syncthreads();

        // phase 3: PV accumulate (rows c, cols j)
        {
            const float4 rr = *(const float4*)&rcol[tj * 4];
#pragma unroll
            for (int a = 0; a < 4; ++a) {
                acc[a * 4 + 0] *= rr.x; acc[a * 4 + 1] *= rr.y;
                acc[a * 4 + 2] *= rr.z; acc[a * 4 + 3] *= rr.w;
            }
#pragma unroll 4
            for (int i = 0; i < 64; ++i) {
                const float4 vv = *(const float4*)&vt[i * 64 + ti * 4];
                const float4 pv = *(const float4*)&St[i * 64 + tj * 4];
                acc[0]  = fmaf(vv.x, pv.x, acc[0]);  acc[1]  = fmaf(vv.x, pv.y, acc[1]);
                acc[2]  = fmaf(vv.x, pv.z, acc[2]);  acc[3]  = fmaf(vv.x, pv.w, acc[3]);
                acc[4]  = fmaf(vv.y, pv.x, acc[4]);  acc[5]  = fmaf(vv.y, pv.y, acc[5]);
                acc[6]  = fmaf(vv.y, pv.z, acc[6]);  acc[7]  = fmaf(vv.y, pv.w, acc[7]);
                acc[8]  = fmaf(vv.z, pv.x, acc[8]);  acc[9]  = fmaf(vv.z, pv.y, acc[9]);
                acc[10] = fmaf(vv.z, pv.z, acc[10]); acc[11] = fmaf(vv.z, pv.w, acc[11]);
                acc[12] = fmaf(vv.w, pv.x, acc[12]); acc[13] = fmaf(vv.w, pv.y, acc[13]);
                acc[14] = fmaf(vv.w, pv.z, acc[14]); acc[15] = fmaf(vv.w, pv.w, acc[15]);
            }
        }
    }

    // store unnormalized PV and per-column m, z
#pragma unroll
    for (int a = 0; a < 4; ++a) {
        float4 o;
        o.x = acc[a * 4 + 0]; o.y = acc[a * 4 + 1]; o.z = acc[a * 4 + 2]; o.w = acc[a * 4 + 3];
        *(float4*)(attu + (size_t)(n * CR + ti * 4 + a) * HW + j0 + tj * 4) = o;
    }
    if (tid < 64) {
        Mcol[(size_t)n * HW + j0 + tid] = mcol[tid];
        Zcol[(size_t)n * HW + j0 + tid] = zcol[tid];
    }
}

// ------------------------------------------------------------- global M, Z per n
__global__ __launch_bounds__(256) void reduce_kernel(
    const float* __restrict__ Mcol, const float* __restrict__ Zcol,
    float* __restrict__ Mn, float* __restrict__ Zn)
{
    const int n = blockIdx.x;
    const int tid = threadIdx.x;
    __shared__ float red[256];

    float lm = -1e30f;
    for (int j = tid; j < HW; j += 256) lm = fmaxf(lm, Mcol[(size_t)n * HW + j]);
    red[tid] = lm; __syncthreads();
    for (int s = 128; s > 0; s >>= 1) {
        if (tid < s) red[tid] = fmaxf(red[tid], red[tid + s]);
        __syncthreads();
    }
    const float M = red[0];
    __syncthreads();

    float ls = 0.f;
    for (int j = tid; j < HW; j += 256)
        ls += Zcol[(size_t)n * HW + j] * __expf(Mcol[(size_t)n * HW + j] - M);
    red[tid] = ls; __syncthreads();
    for (int s = 128; s > 0; s >>= 1) {
        if (tid < s) red[tid] += red[tid + s];
        __syncthreads();
    }
    if (tid == 0) { Mn[n] = M; Zn[n] = red[0]; }
}

// ------------------------------------- 1x1 conv + per-column scale + elementwise
__global__ __launch_bounds__(256) void final_kernel(
    const float* __restrict__ attu, const float* __restrict__ Mcol,
    const float* __restrict__ Mn, const float* __restrict__ Zn,
    const float* __restrict__ watt, const float* __restrict__ batt,
    const float* __restrict__ gco, float* __restrict__ out)
{
    const int idx4 = blockIdx.x * 256 + threadIdx.x;   // one float4 along p
    const int p  = (idx4 % (HW / 4)) * 4;
    const int co = (idx4 / (HW / 4)) % CIN;
    const int n  = idx4 / ((HW / 4) * CIN);

    float t0 = 0.f, t1 = 0.f, t2 = 0.f, t3 = 0.f;
    const float* au = attu + (size_t)n * CR * HW + p;
    const float* wa = watt + (size_t)co * CR;
#pragma unroll 8
    for (int c = 0; c < CR; ++c) {
        const float4 a = *(const float4*)(au + (size_t)c * HW);
        const float wv = wa[c];
        t0 = fmaf(wv, a.x, t0); t1 = fmaf(wv, a.y, t1);
        t2 = fmaf(wv, a.z, t2); t3 = fmaf(wv, a.w, t3);
    }
    const float M = Mn[n];
    const float Zi = 1.f / Zn[n];
    const float4 mc = *(const float4*)(Mcol + (size_t)n * HW + p);
    const float bb = batt[co] + 1.f;   // att2 + 1, factored
    const float4 g = *(const float4*)(gco + (size_t)(n * CIN + co) * HW + p);
    float4 o;
    o.x = g.x * (t0 * __expf(mc.x - M) * Zi + bb);
    o.y = g.y * (t1 * __expf(mc.y - M) * Zi + bb);
    o.z = g.z * (t2 * __expf(mc.z - M) * Zi + bb);
    o.w = g.w * (t3 * __expf(mc.w - M) * Zi + bb);
    *(float4*)(out + (size_t)(n * CIN + co) * HW + p) = o;
}

// --------------------------------------------------------------------- launch
extern "C" void kernel_launch(void* const* d_in, const int* in_sizes, int n_in,
                              void* d_out, int out_size, void* d_ws, size_t ws_size,
                              hipStream_t stream)
{
    (void)in_sizes; (void)n_in; (void)out_size; (void)ws_size;
    const float* fm   = (const float*)d_in[0];
    const float* gco  = (const float*)d_in[1];
    const float* wq   = (const float*)d_in[2];
    const float* bq   = (const float*)d_in[3];
    const float* wk   = (const float*)d_in[4];
    const float* bk   = (const float*)d_in[5];
    const float* wv   = (const float*)d_in[6];
    const float* bv   = (const float*)d_in[7];
    const float* watt = (const float*)d_in[8];
    const float* batt = (const float*)d_in[9];
    float* out = (float*)d_out;
    float* ws  = (float*)d_ws;

    // q/k/v live in d_out as scratch (3*QKV = 6.29M floats <= out_size 8.39M);
    // final_kernel rewrites every element of d_out afterwards.
    float* q = out;
    float* k = q + QKV;
    float* v = k + QKV;
    // ws: attu + Mcol + Zcol + Mn + Zn  (~8.7 MB)
    float* attu = ws;
    float* Mcol = attu + QKV;
    float* Zcol = Mcol + NHW;
    float* Mn   = Zcol + NHW;
    float* Zn   = Mn + NB;

    conv_kernel<3><<<NB * CR, 256, 0, stream>>>(fm, wq, bq, q);
    conv_kernel<5><<<NB * CR, 256, 0, stream>>>(fm, wk, bk, k);
    conv_kernel<7><<<NB * CR, 256, 0, stream>>>(fm, wv, bv, v);
    attn_kernel<<<NB * 64, 256, 0, stream>>>(q, k, v, attu, Mcol, Zcol);
    reduce_kernel<<<NB, 256, 0, stream>>>(Mcol, Zcol, Mn, Zn);
    final_kernel<<<NB * CIN * HW / 1024, 256, 0, stream>>>(
        attu, Mcol, Mn, Zn, watt, batt, gco, out);
}

// Round 2
// 912.336 us; speedup vs baseline: 3.1249x; 3.1249x over previous
//
#include <hip/hip_runtime.h>
#include <math.h>

#define NB 8
#define CIN 256
#define CR 64
#define H 64
#define W 64
#define HW 4096

typedef _Float16 f16;
typedef _Float16 f16x8 __attribute__((ext_vector_type(8)));
typedef _Float16 f16x4 __attribute__((ext_vector_type(4)));
typedef float f32x4 __attribute__((ext_vector_type(4)));

static const size_t QKV = (size_t)NB * CR * HW;   // 2,097,152 elems per q/k/v/attu
static const size_t NHW = (size_t)NB * HW;        // 32,768

// ------------------------------------------------------------- weight prep
// w[co][ci][dy][dx] fp32 -> wT[dy*K+dx][co][ci] fp16
__global__ __launch_bounds__(256) void prep_w(
    const float* __restrict__ src, f16* __restrict__ dst, int KK)
{
    int idx = blockIdx.x * 256 + threadIdx.x;    // < 64*256*KK
    int ci = idx & 255;
    int co = (idx >> 8) & 63;
    int off = idx >> 14;
    dst[((size_t)(off * 64 + co)) * 256 + ci] = (f16)src[((size_t)(co * 256 + ci)) * KK + off];
}

// ---------------------------------------------------------- MFMA conv K x K
// Block: (n, 4-row group). 4 waves; wave w computes output row y0+w,
// 64co x 64x as 4x4 fragments of mfma_f32_16x16x32_f16.
// LDS X: [4 slots][72 cols] rows of 128B (64 ci fp16), XOR-swizzled 16B slots.
// LDS W: [K dx][64 co] rows of 128B (64 ci fp16), XOR-swizzled by co.
template<int K>
__global__ __launch_bounds__(256) void conv_mfma(
    const float* __restrict__ fm, const f16* __restrict__ wT,
    const float* __restrict__ bias, float* __restrict__ dst)
{
    constexpr int P = K / 2;
    constexpr int XROWS = 72;
    constexpr int XBYTES = 4 * XROWS * 128;   // 36864
    constexpr int WBYTES = K * 64 * 128;
    __shared__ __align__(16) unsigned char smem[XBYTES + WBYTES];
    unsigned char* Xl = smem;
    unsigned char* Wl = smem + XBYTES;

    const int n  = blockIdx.x >> 4;
    const int y0 = (blockIdx.x & 15) * 4;
    const int tid = threadIdx.x;
    const int wv  = tid >> 6;
    const int lane = tid & 63;

    // pre-zero halo columns (cols [0,P) and [64+P,72)) once
    {
        int chunk = tid & 7;          // 16B chunk within 128B row
        int colh  = (tid >> 3) & 7;   // 8 halo cols
        int slot  = tid >> 6;
        int col = (colh < P) ? colh : (64 + colh);
        *(uint4*)(Xl + (size_t)(slot * XROWS + col) * 128 + chunk * 16) = uint4{0, 0, 0, 0};
    }

    f32x4 acc[4][4];
#pragma unroll
    for (int i = 0; i < 4; ++i)
#pragma unroll
        for (int j = 0; j < 4; ++j) acc[i][j] = f32x4{0.f, 0.f, 0.f, 0.f};

    const int x = lane;          // staging x for this lane (wave w stages slot w)
    const int xP = x + P;
    const int xkey = (xP & 7) << 4;
    const int lm = lane & 15;
    const int g  = lane >> 4;

    for (int dy = 0; dy < K; ++dy) {
        const int iy = y0 + wv + dy - P;
        const bool yok = (iy >= 0) && (iy < H);
        for (int ch = 0; ch < 4; ++ch) {
            __syncthreads();
            // ---- stage X: 64 ci scalars (coalesced across lanes) -> 16 b64 writes
            {
                unsigned char* wb = Xl + (size_t)(wv * XROWS + xP) * 128;
                if (yok) {
                    const float* s0 = fm + (((size_t)n * CIN + ch * 64) * H + iy) * W + x;
#pragma unroll
                    for (int c4 = 0; c4 < 16; ++c4) {
                        f16x4 pk;
#pragma unroll
                        for (int e = 0; e < 4; ++e)
                            pk[e] = (f16)s0[(size_t)(c4 * 4 + e) * HW];
                        *(f16x4*)(wb + ((c4 * 8) ^ xkey)) = pk;
                    }
                } else {
                    f16x4 z = f16x4{(f16)0.f, (f16)0.f, (f16)0.f, (f16)0.f};
#pragma unroll
                    for (int c4 = 0; c4 < 16; ++c4)
                        *(f16x4*)(wb + ((c4 * 8) ^ xkey)) = z;
                }
            }
            // ---- stage W: K*512 16B chunks
            {
#pragma unroll
                for (int p = 0; p < 2 * K; ++p) {
                    int idx = tid + p * 256;       // < K*512
                    int cig = idx & 7;
                    int co  = (idx >> 3) & 63;
                    int dx  = idx >> 9;
                    const f16* s = wT + ((size_t)((dy * K + dx) * 64 + co)) * 256 + ch * 64 + cig * 8;
                    *(uint4*)(Wl + (size_t)(dx * 64 + co) * 128 + ((cig * 16) ^ ((co & 7) << 4))) =
                        *(const uint4*)s;
                }
            }
            __syncthreads();
            // ---- compute: dx x (2 k-steps) x 16 MFMA
#pragma unroll
            for (int dx = 0; dx < K; ++dx) {
#pragma unroll
                for (int s = 0; s < 2; ++s) {
                    f16x8 a[4], b[4];
#pragma unroll
                    for (int cf = 0; cf < 4; ++cf) {
                        int co = cf * 16 + lm;
                        a[cf] = *(const f16x8*)(Wl + (size_t)(dx * 64 + co) * 128 +
                                                ((s * 64 + g * 16) ^ ((co & 7) << 4)));
                    }
#pragma unroll
                    for (int xf = 0; xf < 4; ++xf) {
                        int col = xf * 16 + lm + dx;
                        b[xf] = *(const f16x8*)(Xl + (size_t)(wv * XROWS + col) * 128 +
                                                ((s * 64 + g * 16) ^ ((col & 7) << 4)));
                    }
#pragma unroll
                    for (int cf = 0; cf < 4; ++cf)
#pragma unroll
                        for (int xf = 0; xf < 4; ++xf)
                            acc[cf][xf] = __builtin_amdgcn_mfma_f32_16x16x32_f16(
                                a[cf], b[xf], acc[cf][xf], 0, 0, 0);
                }
            }
        }
    }

    // epilogue: D col = lane&15 -> x, row = (lane>>4)*4+reg -> co
    const int y = y0 + wv;
#pragma unroll
    for (int cf = 0; cf < 4; ++cf) {
#pragma unroll
        for (int r = 0; r < 4; ++r) {
            int co = cf * 16 + g * 4 + r;
            float bv = bias[co];
#pragma unroll
            for (int xf = 0; xf < 4; ++xf)
                dst[((size_t)(n * CR + co)) * HW + y * W + xf * 16 + lm] = acc[cf][xf][r] + bv;
        }
    }
}

// ------------------------------------------------- fused qk + online softmax + PV
__global__ __launch_bounds__(256) void attn_kernel(
    const float* __restrict__ q, const float* __restrict__ k, const float* __restrict__ v,
    f16* __restrict__ attu, float* __restrict__ Mcol, float* __restrict__ Zcol)
{
    const int n  = blockIdx.x >> 6;
    const int jb = blockIdx.x & 63;
    const int j0 = jb * 64;
    const int tid = threadIdx.x;

    __shared__ float qt[64 * 64];   // [c][j]
    __shared__ float kt[64 * 64];   // [c][i]
    __shared__ float vt[64 * 64];   // [i][c]
    __shared__ float St[64 * 64];   // [i][j]
    __shared__ float mcol[64], zcol[64], rcol[64];
    __shared__ float pm[256], pz[256];

    {
        const int c  = tid >> 2;
        const int jj = (tid & 3) * 16;
        const float* src = q + (size_t)(n * CR + c) * HW + j0 + jj;
#pragma unroll
        for (int e = 0; e < 4; ++e)
            *(float4*)&qt[c * 64 + jj + e * 4] = *(const float4*)(src + e * 4);
    }
    if (tid < 64) { mcol[tid] = -1e30f; zcol[tid] = 0.f; }

    float acc[16];
#pragma unroll
    for (int t = 0; t < 16; ++t) acc[t] = 0.f;

    const int ti = tid & 15;
    const int tj = tid >> 4;
    const int jcol = tid & 63;
    const int qr   = tid >> 6;

    for (int it = 0; it < 64; ++it) {
        const int i0 = it * 64;
        __syncthreads();
        {
            const int c  = tid >> 2;
            const int ii = (tid & 3) * 16;
            const float* ks = k + (size_t)(n * CR + c) * HW + i0 + ii;
            const float* vs = v + (size_t)(n * CR + c) * HW + i0 + ii;
#pragma unroll
            for (int e = 0; e < 4; ++e)
                *(float4*)&kt[c * 64 + ii + e * 4] = *(const float4*)(ks + e * 4);
#pragma unroll
            for (int e = 0; e < 16; ++e)
                vt[(ii + e) * 64 + c] = vs[e];
        }
        __syncthreads();

        float s[16];
#pragma unroll
        for (int t = 0; t < 16; ++t) s[t] = 0.f;
#pragma unroll 8
        for (int c = 0; c < 64; ++c) {
            const float4 kv = *(const float4*)&kt[c * 64 + ti * 4];
            const float4 qv = *(const float4*)&qt[c * 64 + tj * 4];
            s[0]  = fmaf(kv.x, qv.x, s[0]);  s[1]  = fmaf(kv.x, qv.y, s[1]);
            s[2]  = fmaf(kv.x, qv.z, s[2]);  s[3]  = fmaf(kv.x, qv.w, s[3]);
            s[4]  = fmaf(kv.y, qv.x, s[4]);  s[5]  = fmaf(kv.y, qv.y, s[5]);
            s[6]  = fmaf(kv.y, qv.z, s[6]);  s[7]  = fmaf(kv.y, qv.w, s[7]);
            s[8]  = fmaf(kv.z, qv.x, s[8]);  s[9]  = fmaf(kv.z, qv.y, s[9]);
            s[10] = fmaf(kv.z, qv.z, s[10]); s[11] = fmaf(kv.z, qv.w, s[11]);
            s[12] = fmaf(kv.w, qv.x, s[12]); s[13] = fmaf(kv.w, qv.y, s[13]);
            s[14] = fmaf(kv.w, qv.z, s[14]); s[15] = fmaf(kv.w, qv.w, s[15]);
        }
#pragma unroll
        for (int a = 0; a < 4; ++a) {
            float4 o;
            o.x = s[a * 4 + 0]; o.y = s[a * 4 + 1]; o.z = s[a * 4 + 2]; o.w = s[a * 4 + 3];
            *(float4*)&St[(ti * 4 + a) * 64 + tj * 4] = o;
        }
        __syncthreads();

        float lm2 = -1e30f;
#pragma unroll
        for (int t = 0; t < 16; ++t) lm2 = fmaxf(lm2, St[(qr * 16 + t) * 64 + jcol]);
        pm[qr * 64 + jcol] = lm2;
        const float mold = mcol[jcol];
        __syncthreads();

        const float mt = fmaxf(fmaxf(pm[jcol], pm[64 + jcol]),
                               fmaxf(pm[128 + jcol], pm[192 + jcol]));
        const float mnew = fmaxf(mold, mt);
        const float r = __expf(mold - mnew);
        float ps = 0.f;
#pragma unroll
        for (int t = 0; t < 16; ++t) {
            const int idx = (qr * 16 + t) * 64 + jcol;
            const float e = __expf(St[idx] - mnew);
            St[idx] = e;
            ps += e;
        }
        pz[qr * 64 + jcol] = ps;
        __syncthreads();

        if (qr == 0) {
            const float zt = pz[jcol] + pz[64 + jcol] + pz[128 + jcol] + pz[192 + jcol];
            zcol[jcol] = zcol[jcol] * r + zt;
            mcol[jcol] = mnew;
            rcol[jcol] = r;
        }
        __syncthreads();

        {
            const float4 rr = *(const float4*)&rcol[tj * 4];
#pragma unroll
            for (int a = 0; a < 4; ++a) {
                acc[a * 4 + 0] *= rr.x; acc[a * 4 + 1] *= rr.y;
                acc[a * 4 + 2] *= rr.z; acc[a * 4 + 3] *= rr.w;
            }
#pragma unroll 4
            for (int i = 0; i < 64; ++i) {
                const float4 vv = *(const float4*)&vt[i * 64 + ti * 4];
                const float4 pv = *(const float4*)&St[i * 64 + tj * 4];
                acc[0]  = fmaf(vv.x, pv.x, acc[0]);  acc[1]  = fmaf(vv.x, pv.y, acc[1]);
                acc[2]  = fmaf(vv.x, pv.z, acc[2]);  acc[3]  = fmaf(vv.x, pv.w, acc[3]);
                acc[4]  = fmaf(vv.y, pv.x, acc[4]);  acc[5]  = fmaf(vv.y, pv.y, acc[5]);
                acc[6]  = fmaf(vv.y, pv.z, acc[6]);  acc[7]  = fmaf(vv.y, pv.w, acc[7]);
                acc[8]  = fmaf(vv.z, pv.x, acc[8]);  acc[9]  = fmaf(vv.z, pv.y, acc[9]);
                acc[10] = fmaf(vv.z, pv.z, acc[10]); acc[11] = fmaf(vv.z, pv.w, acc[11]);
                acc[12] = fmaf(vv.w, pv.x, acc[12]); acc[13] = fmaf(vv.w, pv.y, acc[13]);
                acc[14] = fmaf(vv.w, pv.z, acc[14]); acc[15] = fmaf(vv.w, pv.w, acc[15]);
            }
        }
    }

#pragma unroll
    for (int a = 0; a < 4; ++a) {
        f16x4 o;
        o[0] = (f16)acc[a * 4 + 0]; o[1] = (f16)acc[a * 4 + 1];
        o[2] = (f16)acc[a * 4 + 2]; o[3] = (f16)acc[a * 4 + 3];
        *(f16x4*)(attu + (size_t)(n * CR + ti * 4 + a) * HW + j0 + tj * 4) = o;
    }
    if (tid < 64) {
        Mcol[(size_t)n * HW + j0 + tid] = mcol[tid];
        Zcol[(size_t)n * HW + j0 + tid] = zcol[tid];
    }
}

// ------------------------------------------------------------- global M, Z per n
__global__ __launch_bounds__(256) void reduce_kernel(
    const float* __restrict__ Mcol, const float* __restrict__ Zcol,
    float* __restrict__ Mn, float* __restrict__ Zn)
{
    const int n = blockIdx.x;
    const int tid = threadIdx.x;
    __shared__ float red[256];

    float lm = -1e30f;
    for (int j = tid; j < HW; j += 256) lm = fmaxf(lm, Mcol[(size_t)n * HW + j]);
    red[tid] = lm; __syncthreads();
    for (int s = 128; s > 0; s >>= 1) {
        if (tid < s) red[tid] = fmaxf(red[tid], red[tid + s]);
        __syncthreads();
    }
    const float M = red[0];
    __syncthreads();

    float ls = 0.f;
    for (int j = tid; j < HW; j += 256)
        ls += Zcol[(size_t)n * HW + j] * __expf(Mcol[(size_t)n * HW + j] - M);
    red[tid] = ls; __syncthreads();
    for (int s = 128; s > 0; s >>= 1) {
        if (tid < s) red[tid] += red[tid + s];
        __syncthreads();
    }
    if (tid == 0) { Mn[n] = M; Zn[n] = red[0]; }
}

// ------------------------------------- 1x1 conv + per-column scale + elementwise
__global__ __launch_bounds__(256) void final_kernel(
    const f16* __restrict__ attu, const float* __restrict__ Mcol,
    const float* __restrict__ Mn, const float* __restrict__ Zn,
    const float* __restrict__ watt, const float* __restrict__ batt,
    const float* __restrict__ gco, float* __restrict__ out)
{
    const int idx4 = blockIdx.x * 256 + threadIdx.x;
    const int p  = (idx4 % (HW / 4)) * 4;
    const int co = (idx4 / (HW / 4)) % CIN;
    const int n  = idx4 / ((HW / 4) * CIN);

    float t0 = 0.f, t1 = 0.f, t2 = 0.f, t3 = 0.f;
    const f16* au = attu + (size_t)n * CR * HW + p;
    const float* wa = watt + (size_t)co * CR;
#pragma unroll 8
    for (int c = 0; c < CR; ++c) {
        const f16x4 a = *(const f16x4*)(au + (size_t)c * HW);
        const float wv = wa[c];
        t0 = fmaf(wv, (float)a[0], t0); t1 = fmaf(wv, (float)a[1], t1);
        t2 = fmaf(wv, (float)a[2], t2); t3 = fmaf(wv, (float)a[3], t3);
    }
    const float M = Mn[n];
    const float Zi = 1.f / Zn[n];
    const float4 mc = *(const float4*)(Mcol + (size_t)n * HW + p);
    const float bb = batt[co] + 1.f;
    const float4 g = *(const float4*)(gco + (size_t)(n * CIN + co) * HW + p);
    float4 o;
    o.x = g.x * (t0 * __expf(mc.x - M) * Zi + bb);
    o.y = g.y * (t1 * __expf(mc.y - M) * Zi + bb);
    o.z = g.z * (t2 * __expf(mc.z - M) * Zi + bb);
    o.w = g.w * (t3 * __expf(mc.w - M) * Zi + bb);
    *(float4*)(out + (size_t)(n * CIN + co) * HW + p) = o;
}

// --------------------------------------------------------------------- launch
extern "C" void kernel_launch(void* const* d_in, const int* in_sizes, int n_in,
                              void* d_out, int out_size, void* d_ws, size_t ws_size,
                              hipStream_t stream)
{
    (void)in_sizes; (void)n_in; (void)out_size; (void)ws_size;
    const float* fm   = (const float*)d_in[0];
    const float* gco  = (const float*)d_in[1];
    const float* wq   = (const float*)d_in[2];
    const float* bq   = (const float*)d_in[3];
    const float* wk   = (const float*)d_in[4];
    const float* bk   = (const float*)d_in[5];
    const float* wv   = (const float*)d_in[6];
    const float* bv   = (const float*)d_in[7];
    const float* watt = (const float*)d_in[8];
    const float* batt = (const float*)d_in[9];
    float* out = (float*)d_out;

    // q/k/v fp32 live in d_out (final_kernel rewrites every output element)
    float* q = out;
    float* k = q + QKV;
    float* v = k + QKV;

    // ws layout (bytes): wTq | wTk | wTv (f16) | attu (f16) | Mcol | Zcol | Mn | Zn
    unsigned char* wsb = (unsigned char*)d_ws;
    f16* wTq = (f16*)(wsb);                                   //  9*16384 f16
    f16* wTk = (f16*)(wsb + 294912);                          // 25*16384 f16
    f16* wTv = (f16*)(wsb + 1114112);                         // 49*16384 f16
    f16* attu = (f16*)(wsb + 2719744);                        // 2,097,152 f16
    float* Mcol = (float*)(wsb + 6914048);                    // 32768 f32
    float* Zcol = (float*)(wsb + 7045120);                    // 32768 f32
    float* Mn   = (float*)(wsb + 7176192);                    // 8 f32
    float* Zn   = (float*)(wsb + 7176224);                    // 8 f32

    prep_w<<<576, 256, 0, stream>>>(wq, wTq, 9);
    prep_w<<<1600, 256, 0, stream>>>(wk, wTk, 25);
    prep_w<<<3136, 256, 0, stream>>>(wv, wTv, 49);

    conv_mfma<3><<<NB * 16, 256, 0, stream>>>(fm, wTq, bq, q);
    conv_mfma<5><<<NB * 16, 256, 0, stream>>>(fm, wTk, bk, k);
    conv_mfma<7><<<NB * 16, 256, 0, stream>>>(fm, wTv, bv, v);

    attn_kernel<<<NB * 64, 256, 0, stream>>>(q, k, v, attu, Mcol, Zcol);
    reduce_kernel<<<NB, 256, 0, stream>>>(Mcol, Zcol, Mn, Zn);
    final_kernel<<<NB * CIN * HW / 1024, 256, 0, stream>>>(
        attu, Mcol, Mn, Zn, watt, batt, gco, out);
}

// Round 4
// 405.591 us; speedup vs baseline: 7.0292x; 2.2494x over previous
//
#include <hip/hip_runtime.h>
#include <math.h>

#define NB 8
#define CIN 256
#define CR 64
#define H 64
#define W 64
#define HW 4096

typedef _Float16 f16;
typedef _Float16 f16x8 __attribute__((ext_vector_type(8)));
typedef _Float16 f16x4 __attribute__((ext_vector_type(4)));
typedef float f32x4 __attribute__((ext_vector_type(4)));

static const size_t QKV = (size_t)NB * CR * HW;   // 2,097,152 elems per q/k/v buffer

// ------------------------------------------------------------- weight prep
// w[co][ci][dy][dx] fp32 -> wT[dy*K+dx][co][ci] fp16
__global__ __launch_bounds__(256) void prep_w(
    const float* __restrict__ src, f16* __restrict__ dst, int KK)
{
    int idx = blockIdx.x * 256 + threadIdx.x;    // < 64*256*KK
    int ci = idx & 255;
    int co = (idx >> 8) & 63;
    int off = idx >> 14;
    dst[((size_t)(off * 64 + co)) * 256 + ci] = (f16)src[((size_t)(co * 256 + ci)) * KK + off];
}

// ---------------------------------------------------------- MFMA conv K x K
// LAYOUT 0: dst transposed [n][x][c] f16 (for q, k).  LAYOUT 1: natural [n][c][x] f16 (v).
template<int K, int LAYOUT>
__global__ __launch_bounds__(256) void conv_mfma(
    const float* __restrict__ fm, const f16* __restrict__ wT,
    const float* __restrict__ bias, f16* __restrict__ dst)
{
    constexpr int P = K / 2;
    constexpr int XROWS = 72;
    constexpr int XBYTES = 4 * XROWS * 128;   // 36864
    constexpr int WBYTES = K * 64 * 128;
    __shared__ __align__(16) unsigned char smem[XBYTES + WBYTES];
    unsigned char* Xl = smem;
    unsigned char* Wl = smem + XBYTES;

    const int n  = blockIdx.x >> 4;
    const int y0 = (blockIdx.x & 15) * 4;
    const int tid = threadIdx.x;
    const int wv  = tid >> 6;
    const int lane = tid & 63;

    // pre-zero halo columns (cols [0,P) and [64+P,72)) once
    {
        int chunk = tid & 7;
        int colh  = (tid >> 3) & 7;
        int slot  = tid >> 6;
        int col = (colh < P) ? colh : (64 + colh);
        *(uint4*)(Xl + (size_t)(slot * XROWS + col) * 128 + chunk * 16) = uint4{0, 0, 0, 0};
    }

    f32x4 acc[4][4];
#pragma unroll
    for (int i = 0; i < 4; ++i)
#pragma unroll
        for (int j = 0; j < 4; ++j) acc[i][j] = f32x4{0.f, 0.f, 0.f, 0.f};

    const int x = lane;
    const int xP = x + P;
    const int xkey = (xP & 7) << 4;
    const int lm = lane & 15;
    const int g  = lane >> 4;

    for (int dy = 0; dy < K; ++dy) {
        const int iy = y0 + wv + dy - P;
        const bool yok = (iy >= 0) && (iy < H);
        for (int ch = 0; ch < 4; ++ch) {
            __syncthreads();
            {
                unsigned char* wb = Xl + (size_t)(wv * XROWS + xP) * 128;
                if (yok) {
                    const float* s0 = fm + (((size_t)n * CIN + ch * 64) * H + iy) * W + x;
#pragma unroll
                    for (int c4 = 0; c4 < 16; ++c4) {
                        f16x4 pk;
#pragma unroll
                        for (int e = 0; e < 4; ++e)
                            pk[e] = (f16)s0[(size_t)(c4 * 4 + e) * HW];
                        *(f16x4*)(wb + ((c4 * 8) ^ xkey)) = pk;
                    }
                } else {
                    f16x4 z = f16x4{(f16)0.f, (f16)0.f, (f16)0.f, (f16)0.f};
#pragma unroll
                    for (int c4 = 0; c4 < 16; ++c4)
                        *(f16x4*)(wb + ((c4 * 8) ^ xkey)) = z;
                }
            }
            {
#pragma unroll
                for (int p = 0; p < 2 * K; ++p) {
                    int idx = tid + p * 256;
                    int cig = idx & 7;
                    int co  = (idx >> 3) & 63;
                    int dx  = idx >> 9;
                    const f16* s = wT + ((size_t)((dy * K + dx) * 64 + co)) * 256 + ch * 64 + cig * 8;
                    *(uint4*)(Wl + (size_t)(dx * 64 + co) * 128 + ((cig * 16) ^ ((co & 7) << 4))) =
                        *(const uint4*)s;
                }
            }
            __syncthreads();
#pragma unroll
            for (int dx = 0; dx < K; ++dx) {
#pragma unroll
                for (int s = 0; s < 2; ++s) {
                    f16x8 a[4], b[4];
#pragma unroll
                    for (int cf = 0; cf < 4; ++cf) {
                        int co = cf * 16 + lm;
                        a[cf] = *(const f16x8*)(Wl + (size_t)(dx * 64 + co) * 128 +
                                                ((s * 64 + g * 16) ^ ((co & 7) << 4)));
                    }
#pragma unroll
                    for (int xf = 0; xf < 4; ++xf) {
                        int col = xf * 16 + lm + dx;
                        b[xf] = *(const f16x8*)(Xl + (size_t)(wv * XROWS + col) * 128 +
                                                ((s * 64 + g * 16) ^ ((col & 7) << 4)));
                    }
#pragma unroll
                    for (int cf = 0; cf < 4; ++cf)
#pragma unroll
                        for (int xf = 0; xf < 4; ++xf)
                            acc[cf][xf] = __builtin_amdgcn_mfma_f32_16x16x32_f16(
                                a[cf], b[xf], acc[cf][xf], 0, 0, 0);
                }
            }
        }
    }

    // epilogue: D col=lane&15 -> x, row=(lane>>4)*4+reg -> co
    const int y = y0 + wv;
#pragma unroll
    for (int cf = 0; cf < 4; ++cf) {
        const float4 bv = *(const float4*)(bias + cf * 16 + g * 4);
        if (LAYOUT == 0) {
#pragma unroll
            for (int xf = 0; xf < 4; ++xf) {
                f16x4 pk;
#pragma unroll
                for (int r = 0; r < 4; ++r)
                    pk[r] = (f16)(acc[cf][xf][r] + ((const float*)&bv)[r]);
                *(f16x4*)(dst + ((size_t)n * HW + y * W + xf * 16 + lm) * 64 + cf * 16 + g * 4) = pk;
            }
        } else {
#pragma unroll
            for (int r = 0; r < 4; ++r) {
                const int co = cf * 16 + g * 4 + r;
#pragma unroll
                for (int xf = 0; xf < 4; ++xf)
                    dst[((size_t)(n * CR + co)) * HW + y * W + xf * 16 + lm] =
                        (f16)(acc[cf][xf][r] + ((const float*)&bv)[r]);
            }
        }
    }
}

// ------------------------------------------------- fused MFMA attention
// block = (n, jt). 4 waves; wave w owns 16 columns j = jt*64 + w*16 + (lane&15),
// iterates all 4096 i in 64-i tiles. Softmax state (m,z) per column in registers.
__global__ __launch_bounds__(256, 2) void attn_mfma(
    const f16* __restrict__ qT, const f16* __restrict__ kT, const f16* __restrict__ vv,
    f16* __restrict__ attu, float* __restrict__ Mcol, float* __restrict__ Zcol)
{
    const int bid = blockIdx.x;
    const int jt = bid & 63;
    const int n  = bid >> 6;
    const int j0 = jt * 64;
    const int tid = threadIdx.x;
    const int wv = tid >> 6;
    const int lane = tid & 63;
    const int lm = lane & 15;
    const int g  = lane >> 4;
    const int key = (lm & 7) << 4;

    __shared__ __align__(16) f16 Qt[64 * 64];
    __shared__ __align__(16) f16 Kt[64 * 64];
    __shared__ __align__(16) f16 Vt[64 * 64];

    // stage Qt once: qT[n][j0+j][c] -> rows [j][64c], XOR-swizzled 16B slots
    {
        const int r = tid >> 2;
        const f16* src = qT + ((size_t)n * HW + j0 + r) * 64;
#pragma unroll
        for (int h = 0; h < 2; ++h) {
            const int ch = (tid & 3) * 2 + h;
            *(uint4*)((char*)Qt + r * 128 + ((ch * 16) ^ ((r & 7) << 4))) =
                *(const uint4*)(src + ch * 8);
        }
    }

    float m = -1e30f, z = 0.f;
    f32x4 accp[4];
#pragma unroll
    for (int c = 0; c < 4; ++c) accp[c] = f32x4{0.f, 0.f, 0.f, 0.f};

    for (int it = 0; it < 64; ++it) {
        const int i0 = it * 64;
        __syncthreads();
        // stage Kt ([i][c]) and Vt ([c][i])
        {
            const int r = tid >> 2;
            const f16* ks = kT + ((size_t)n * HW + i0 + r) * 64;
            const f16* vs = vv + ((size_t)n * CR + r) * HW + i0;
#pragma unroll
            for (int h = 0; h < 2; ++h) {
                const int ch = (tid & 3) * 2 + h;
                *(uint4*)((char*)Kt + r * 128 + ((ch * 16) ^ ((r & 7) << 4))) =
                    *(const uint4*)(ks + ch * 8);
                *(uint4*)((char*)Vt + r * 128 + ((ch * 16) ^ ((r & 7) << 4))) =
                    *(const uint4*)(vs + ch * 8);
            }
        }
        __syncthreads();

        // ---- QK: S[i][j], wave covers 64 i (4 frags) x its 16 j
        f32x4 sacc[4];
#pragma unroll
        for (int f = 0; f < 4; ++f) sacc[f] = f32x4{0.f, 0.f, 0.f, 0.f};
#pragma unroll
        for (int ks = 0; ks < 2; ++ks) {
            const int off = (ks * 64 + g * 16);
            const f16x8 B = *(const f16x8*)((char*)Qt + (wv * 16 + lm) * 128 + (off ^ key));
#pragma unroll
            for (int f = 0; f < 4; ++f) {
                const f16x8 A = *(const f16x8*)((char*)Kt + (f * 16 + lm) * 128 + (off ^ key));
                sacc[f] = __builtin_amdgcn_mfma_f32_16x16x32_f16(A, B, sacc[f], 0, 0, 0);
            }
        }

        // ---- online softmax (column j = j0 + wv*16 + lm, lane-local)
        float mt = -1e30f;
#pragma unroll
        for (int f = 0; f < 4; ++f)
#pragma unroll
            for (int r = 0; r < 4; ++r) mt = fmaxf(mt, sacc[f][r]);
        mt = fmaxf(mt, __shfl_xor(mt, 16));
        mt = fmaxf(mt, __shfl_xor(mt, 32));
        const float mnew = fmaxf(m, mt);
        const float rr = __expf(m - mnew);
        m = mnew;

        f16x4 p16[4];
        float zt = 0.f;
#pragma unroll
        for (int f = 0; f < 4; ++f) {
#pragma unroll
            for (int r = 0; r < 4; ++r) {
                const float e = __expf(sacc[f][r] - mnew);
                zt += e;
                p16[f][r] = (f16)e;
            }
        }
        zt += __shfl_xor(zt, 16);
        zt += __shfl_xor(zt, 32);
        z = z * rr + zt;

#pragma unroll
        for (int cf = 0; cf < 4; ++cf) {
            accp[cf][0] *= rr; accp[cf][1] *= rr;
            accp[cf][2] *= rr; accp[cf][3] *= rr;
        }

        // ---- PV: att[c][j] += V[c][i-tile] * P
#pragma unroll
        for (int cf = 0; cf < 4; ++cf) {
#pragma unroll
            for (int f = 0; f < 4; ++f) {
                const f16x4 A = *(const f16x4*)((char*)Vt + (cf * 16 + lm) * 128 +
                                                ((f * 32 + g * 8) ^ key));
                accp[cf] = __builtin_amdgcn_mfma_f32_16x16x16f16(A, p16[f], accp[cf], 0, 0, 0);
            }
        }
    }

    // epilogue: attu[n][c][j] f16; Mcol/Zcol[n][j]
    const size_t abase = (size_t)n * CR;
    const int j = j0 + wv * 16 + lm;
#pragma unroll
    for (int cf = 0; cf < 4; ++cf)
#pragma unroll
        for (int r = 0; r < 4; ++r)
            attu[(abase + cf * 16 + g * 4 + r) * HW + j] = (f16)accp[cf][r];
    if (g == 0) {
        Mcol[(size_t)n * HW + j] = m;
        Zcol[(size_t)n * HW + j] = z;
    }
}

// ------------------------------------------------------------- global M, Z per n
__global__ __launch_bounds__(256) void reduce_kernel(
    const float* __restrict__ Mcol, const float* __restrict__ Zcol,
    float* __restrict__ Mn, float* __restrict__ Zn)
{
    const int n = blockIdx.x;
    const int tid = threadIdx.x;
    __shared__ float red[256];

    float lm = -1e30f;
    for (int j = tid; j < HW; j += 256) lm = fmaxf(lm, Mcol[(size_t)n * HW + j]);
    red[tid] = lm; __syncthreads();
    for (int s = 128; s > 0; s >>= 1) {
        if (tid < s) red[tid] = fmaxf(red[tid], red[tid + s]);
        __syncthreads();
    }
    const float M = red[0];
    __syncthreads();

    float ls = 0.f;
    for (int j = tid; j < HW; j += 256)
        ls += Zcol[(size_t)n * HW + j] * __expf(Mcol[(size_t)n * HW + j] - M);
    red[tid] = ls; __syncthreads();
    for (int s = 128; s > 0; s >>= 1) {
        if (tid < s) red[tid] += red[tid + s];
        __syncthreads();
    }
    if (tid == 0) { Mn[n] = M; Zn[n] = red[0]; }
}

// ------------------------- 1x1 conv + per-column scale + elementwise
__global__ __launch_bounds__(256) void final_kernel(
    const f16* __restrict__ attu, const float* __restrict__ Mcol,
    const float* __restrict__ Mn, const float* __restrict__ Zn,
    const float* __restrict__ watt, const float* __restrict__ batt,
    const float* __restrict__ gco, float* __restrict__ out)
{
    const int idx4 = blockIdx.x * 256 + threadIdx.x;
    const int p  = (idx4 % (HW / 4)) * 4;
    const int co = (idx4 / (HW / 4)) % CIN;
    const int n  = idx4 / ((HW / 4) * CIN);

    float t0[4] = {0.f, 0.f, 0.f, 0.f};
    const f16* a0 = attu + ((size_t)n * CR) * HW + p;
    const float* wa = watt + (size_t)co * CR;
#pragma unroll 8
    for (int c = 0; c < CR; ++c) {
        const f16x4 x0 = *(const f16x4*)(a0 + (size_t)c * HW);
        const float wv = wa[c];
#pragma unroll
        for (int e = 0; e < 4; ++e)
            t0[e] = fmaf(wv, (float)x0[e], t0[e]);
    }
    const float M = Mn[n];
    const float Zi = 1.f / Zn[n];
    const float4 mc0 = *(const float4*)(Mcol + (size_t)n * HW + p);
    const float bb = batt[co] + 1.f;
    const float4 gv = *(const float4*)(gco + (size_t)(n * CIN + co) * HW + p);
    float4 o;
    o.x = gv.x * (t0[0] * __expf(mc0.x - M) * Zi + bb);
    o.y = gv.y * (t0[1] * __expf(mc0.y - M) * Zi + bb);
    o.z = gv.z * (t0[2] * __expf(mc0.z - M) * Zi + bb);
    o.w = gv.w * (t0[3] * __expf(mc0.w - M) * Zi + bb);
    *(float4*)(out + (size_t)(n * CIN + co) * HW + p) = o;
}

// --------------------------------------------------------------------- launch
extern "C" void kernel_launch(void* const* d_in, const int* in_sizes, int n_in,
                              void* d_out, int out_size, void* d_ws, size_t ws_size,
                              hipStream_t stream)
{
    (void)in_sizes; (void)n_in; (void)out_size; (void)ws_size;
    const float* fm   = (const float*)d_in[0];
    const float* gco  = (const float*)d_in[1];
    const float* wq   = (const float*)d_in[2];
    const float* bq   = (const float*)d_in[3];
    const float* wk   = (const float*)d_in[4];
    const float* bk   = (const float*)d_in[5];
    const float* wv   = (const float*)d_in[6];
    const float* bv   = (const float*)d_in[7];
    const float* watt = (const float*)d_in[8];
    const float* batt = (const float*)d_in[9];
    float* out = (float*)d_out;

    // f16 conv outputs live in d_out (12 MB of 33.5 MB); dead before final_kernel
    // writes out, so no read/write overlap with the output pass.
    f16* qT   = (f16*)out;            // [n][j][c]   4 MB
    f16* kT   = qT + QKV;             // [n][i][c]   4 MB
    f16* vvb  = kT + QKV;             // [n][c][i]   4 MB

    // ws: wTq | wTk | wTv | attu | Mcol | Zcol | Mn | Zn  (7.18 MB, = round-1 layout)
    unsigned char* wsb = (unsigned char*)d_ws;
    f16* wTq = (f16*)(wsb);                                   //  9*16384 f16
    f16* wTk = (f16*)(wsb + 294912);                          // 25*16384 f16
    f16* wTv = (f16*)(wsb + 1114112);                         // 49*16384 f16
    f16* attu = (f16*)(wsb + 2719744);                        // [n][c][j] f16, 4 MB
    float* Mcol = (float*)(wsb + 6914048);                    // [n][4096] f32
    float* Zcol = (float*)(wsb + 7045120);                    // [n][4096] f32
    float* Mn   = (float*)(wsb + 7176192);                    // 8 f32
    float* Zn   = (float*)(wsb + 7176224);                    // 8 f32

    prep_w<<<576, 256, 0, stream>>>(wq, wTq, 9);
    prep_w<<<1600, 256, 0, stream>>>(wk, wTk, 25);
    prep_w<<<3136, 256, 0, stream>>>(wv, wTv, 49);

    conv_mfma<3, 0><<<NB * 16, 256, 0, stream>>>(fm, wTq, bq, qT);
    conv_mfma<5, 0><<<NB * 16, 256, 0, stream>>>(fm, wTk, bk, kT);
    conv_mfma<7, 1><<<NB * 16, 256, 0, stream>>>(fm, wTv, bv, vvb);

    attn_mfma<<<NB * 64, 256, 0, stream>>>(qT, kT, vvb, attu, Mcol, Zcol);
    reduce_kernel<<<NB, 256, 0, stream>>>(Mcol, Zcol, Mn, Zn);
    final_kernel<<<NB * CIN * HW / 1024, 256, 0, stream>>>(
        attu, Mcol, Mn, Zn, watt, batt, gco, out);
}

// Round 5
// 290.999 us; speedup vs baseline: 9.7972x; 1.3938x over previous
//
#include <hip/hip_runtime.h>
#include <math.h>

#define NB 8
#define CIN 256
#define CR 64
#define H 64
#define W 64
#define HW 4096

typedef _Float16 f16;
typedef _Float16 f16x8 __attribute__((ext_vector_type(8)));
typedef _Float16 f16x4 __attribute__((ext_vector_type(4)));
typedef float f32x4 __attribute__((ext_vector_type(4)));

static const size_t QKV = (size_t)NB * CR * HW;   // 2,097,152 elems per q/k/v buffer

// ------------------------------------------------------------- weight prep
// w[co][ci][dy][dx] fp32 -> wT[dy*K+dx][co][ci] fp16
__global__ __launch_bounds__(256) void prep_w(
    const float* __restrict__ src, f16* __restrict__ dst, int KK)
{
    int idx = blockIdx.x * 256 + threadIdx.x;    // < 64*256*KK
    int ci = idx & 255;
    int co = (idx >> 8) & 63;
    int off = idx >> 14;
    dst[((size_t)(off * 64 + co)) * 256 + ci] = (f16)src[((size_t)(co * 256 + ci)) * KK + off];
}

// ------------------------------------------------------- feature-map transpose
// fm f32 [n][ci][y][x] -> fmT f16 [n][y*64+x][ci]
__global__ __launch_bounds__(256) void transpose_fm(
    const float* __restrict__ fm, f16* __restrict__ fmT)
{
    const int y = blockIdx.x & 63;
    const int n = blockIdx.x >> 6;
    const int tid = threadIdx.x;
    __shared__ f16x4 tile[64 * 64];   // [x][slot], slot XOR-swizzled by x
    const int xw = tid & 63;
    const int wv = tid >> 6;
    const float* s0 = fm + ((size_t)n * CIN) * HW + y * W + xw;
#pragma unroll
    for (int cc = 0; cc < 16; ++cc) {
        const int slot = wv * 16 + cc;            // ci = slot*4 + e
        const float* s = s0 + (size_t)(slot * 4) * HW;
        f16x4 pk;
#pragma unroll
        for (int e = 0; e < 4; ++e) pk[e] = (f16)s[(size_t)e * HW];
        tile[xw * 64 + (slot ^ xw)] = pk;
    }
    __syncthreads();
    f16x4* dst = (f16x4*)fmT + ((size_t)n * HW + y * W) * 64;
#pragma unroll
    for (int it = 0; it < 16; ++it) {
        const int idx = tid + it * 256;           // < 4096
        const int x = idx >> 6;
        const int slot = idx & 63;
        dst[x * 64 + slot] = tile[x * 64 + (slot ^ x)];
    }
}

// ---------------------------------------------------------- MFMA conv K x K
// Grid 256 blocks (n, 2-row group), 512 threads = 8 waves (row r, co-half h, k-half sw).
// X from fmT (vectorized), W from wT; both XOR-swizzled 128B LDS rows.
// 2-way k-split accumulators merged through LDS at the end.
// LAYOUT 0: dst [n][p][c] f16 (q, k).  LAYOUT 1: dst [n][c][p] f16 (v).
template<int K, int LAYOUT>
__global__ __launch_bounds__(512) void conv_mfma(
    const f16* __restrict__ fmT, const f16* __restrict__ wT,
    const float* __restrict__ bias, f16* __restrict__ dst)
{
    constexpr int P = K / 2;
    constexpr int XBYTES = 2 * 72 * 128;          // 18432
    constexpr int WBYTES = K * 64 * 128;
    constexpr int TBYTES = XBYTES + WBYTES;
    constexpr int SBYTES = (TBYTES > 32768) ? TBYTES : 32768;
    __shared__ __align__(16) unsigned char smem[SBYTES];
    unsigned char* Xl = smem;
    unsigned char* Wl = smem + XBYTES;

    const int bid0 = blockIdx.x;
    const int bid = (bid0 & 7) * 32 + (bid0 >> 3);   // XCD swizzle, 256 = 8*32
    const int n  = bid >> 5;
    const int y0 = (bid & 31) * 2;
    const int tid = threadIdx.x;
    const int w = tid >> 6;
    const int lane = tid & 63;
    const int r  = w >> 2;        // row within block
    const int h  = (w >> 1) & 1;  // co half
    const int sw = w & 1;         // k half (32-ci sub-chunk)
    const int lm = lane & 15;
    const int g  = lane >> 4;

    // zero halo columns once (cols [0,P) and [64+P,72) of both slots)
    if (tid < 128) {
        const int sl = tid >> 6;
        const int cidx = (tid >> 3) & 7;
        const int chunk = tid & 7;
        const int col = (cidx < P) ? cidx : (64 + cidx);
        *(uint4*)(Xl + (size_t)(sl * 72 + col) * 128 + chunk * 16) = uint4{0, 0, 0, 0};
    }

    f32x4 acc[2][4];
#pragma unroll
    for (int i = 0; i < 2; ++i)
#pragma unroll
        for (int j = 0; j < 4; ++j) acc[i][j] = f32x4{0.f, 0.f, 0.f, 0.f};

    for (int dy = 0; dy < K; ++dy) {
        for (int ch = 0; ch < 4; ++ch) {
            __syncthreads();
            // ---- stage X: 2 rows x 64 x x 64 ci(ch) = 1024 uint4, 2/thread
#pragma unroll
            for (int p = 0; p < 2; ++p) {
                const int idx = tid + p * 512;
                const int sl = idx >> 9;
                const int x = (idx >> 3) & 63;
                const int chunk = idx & 7;
                const int iy = y0 + sl + dy - P;
                uint4 val = uint4{0, 0, 0, 0};
                if (iy >= 0 && iy < H)
                    val = *(const uint4*)(fmT + ((size_t)n * HW + iy * 64 + x) * 256 +
                                          ch * 64 + chunk * 8);
                *(uint4*)(Xl + (size_t)(sl * 72 + x + P) * 128 +
                          ((chunk * 16) ^ (((x + P) & 7) << 4))) = val;
            }
            // ---- stage W: K*512 uint4, K/thread
#pragma unroll
            for (int p = 0; p < K; ++p) {
                const int idx = tid + p * 512;
                const int cig = idx & 7;
                const int co  = (idx >> 3) & 63;
                const int dx  = idx >> 9;
                const f16* s = wT + ((size_t)((dy * K + dx) * 64 + co)) * 256 + ch * 64 + cig * 8;
                *(uint4*)(Wl + (size_t)(dx * 64 + co) * 128 +
                          ((cig * 16) ^ ((co & 7) << 4))) = *(const uint4*)s;
            }
            __syncthreads();
            // ---- compute: per wave dx(K) x 2cf x 4xf MFMA, one 32-ci k-half
#pragma unroll
            for (int dx = 0; dx < K; ++dx) {
                f16x8 a[2], b[4];
#pragma unroll
                for (int cf = 0; cf < 2; ++cf) {
                    const int co = h * 32 + cf * 16 + lm;
                    a[cf] = *(const f16x8*)(Wl + (size_t)(dx * 64 + co) * 128 +
                                            ((sw * 64 + g * 16) ^ ((co & 7) << 4)));
                }
#pragma unroll
                for (int xf = 0; xf < 4; ++xf) {
                    const int col = xf * 16 + lm + dx;
                    b[xf] = *(const f16x8*)(Xl + (size_t)(r * 72 + col) * 128 +
                                            ((sw * 64 + g * 16) ^ ((col & 7) << 4)));
                }
#pragma unroll
                for (int cf = 0; cf < 2; ++cf)
#pragma unroll
                    for (int xf = 0; xf < 4; ++xf)
                        acc[cf][xf] = __builtin_amdgcn_mfma_f32_16x16x32_f16(
                            a[cf], b[xf], acc[cf][xf], 0, 0, 0);
            }
        }
    }

    // ---- merge k-halves: sw=1 waves write acc, sw=0 waves add
    __syncthreads();
    {
        const int mslot = r * 2 + h;
        if (sw == 1) {
#pragma unroll
            for (int cf = 0; cf < 2; ++cf)
#pragma unroll
                for (int xf = 0; xf < 4; ++xf)
                    *(f32x4*)(smem + (size_t)(mslot * 64 + lane) * 128 +
                              (((cf * 4 + xf) * 16) ^ ((lane & 7) << 4))) = acc[cf][xf];
        }
        __syncthreads();
        if (sw == 0) {
#pragma unroll
            for (int cf = 0; cf < 2; ++cf)
#pragma unroll
                for (int xf = 0; xf < 4; ++xf)
                    acc[cf][xf] += *(const f32x4*)(smem + (size_t)(mslot * 64 + lane) * 128 +
                                                   (((cf * 4 + xf) * 16) ^ ((lane & 7) << 4)));
        }
    }

    // ---- epilogue (sw=0 waves): D col=lm -> x, row=g*4+reg -> co offset
    if (sw == 0) {
        const int y = y0 + r;
#pragma unroll
        for (int cf = 0; cf < 2; ++cf) {
            const float4 bv = *(const float4*)(bias + h * 32 + cf * 16 + g * 4);
            if (LAYOUT == 0) {
#pragma unroll
                for (int xf = 0; xf < 4; ++xf) {
                    f16x4 pk;
#pragma unroll
                    for (int e = 0; e < 4; ++e)
                        pk[e] = (f16)(acc[cf][xf][e] + ((const float*)&bv)[e]);
                    *(f16x4*)(dst + ((size_t)n * HW + y * W + xf * 16 + lm) * 64 +
                              h * 32 + cf * 16 + g * 4) = pk;
                }
            } else {
#pragma unroll
                for (int e = 0; e < 4; ++e) {
                    const int co = h * 32 + cf * 16 + g * 4 + e;
#pragma unroll
                    for (int xf = 0; xf < 4; ++xf)
                        dst[((size_t)(n * CR + co)) * HW + y * W + xf * 16 + lm] =
                            (f16)(acc[cf][xf][e] + ((const float*)&bv)[e]);
                }
            }
        }
    }
}

// ------------------------------------------------- fused MFMA attention
// block = (n, jt). 4 waves; wave w owns 16 columns j = jt*64 + w*16 + (lane&15),
// iterates all 4096 i in 64-i tiles. Softmax state (m,z) per column in registers.
__global__ __launch_bounds__(256, 2) void attn_mfma(
    const f16* __restrict__ qT, const f16* __restrict__ kT, const f16* __restrict__ vv,
    f16* __restrict__ attu, float* __restrict__ Mcol, float* __restrict__ Zcol)
{
    const int bid0 = blockIdx.x;
    const int bid = (bid0 & 7) * 64 + (bid0 >> 3);   // XCD swizzle, 512 = 8*64
    const int jt = bid & 63;
    const int n  = bid >> 6;
    const int j0 = jt * 64;
    const int tid = threadIdx.x;
    const int wv = tid >> 6;
    const int lane = tid & 63;
    const int lm = lane & 15;
    const int g  = lane >> 4;
    const int key = (lm & 7) << 4;

    __shared__ __align__(16) f16 Qt[64 * 64];
    __shared__ __align__(16) f16 Kt[64 * 64];
    __shared__ __align__(16) f16 Vt[64 * 64];

    // stage Qt once: qT[n][j0+j][c] -> rows [j][64c], XOR-swizzled 16B slots
    {
        const int r = tid >> 2;
        const f16* src = qT + ((size_t)n * HW + j0 + r) * 64;
#pragma unroll
        for (int h = 0; h < 2; ++h) {
            const int ch = (tid & 3) * 2 + h;
            *(uint4*)((char*)Qt + r * 128 + ((ch * 16) ^ ((r & 7) << 4))) =
                *(const uint4*)(src + ch * 8);
        }
    }

    float m = -1e30f, z = 0.f;
    f32x4 accp[4];
#pragma unroll
    for (int c = 0; c < 4; ++c) accp[c] = f32x4{0.f, 0.f, 0.f, 0.f};

    for (int it = 0; it < 64; ++it) {
        const int i0 = it * 64;
        __syncthreads();
        // stage Kt ([i][c]) and Vt ([c][i])
        {
            const int r = tid >> 2;
            const f16* ks = kT + ((size_t)n * HW + i0 + r) * 64;
            const f16* vs = vv + ((size_t)n * CR + r) * HW + i0;
#pragma unroll
            for (int h = 0; h < 2; ++h) {
                const int ch = (tid & 3) * 2 + h;
                *(uint4*)((char*)Kt + r * 128 + ((ch * 16) ^ ((r & 7) << 4))) =
                    *(const uint4*)(ks + ch * 8);
                *(uint4*)((char*)Vt + r * 128 + ((ch * 16) ^ ((r & 7) << 4))) =
                    *(const uint4*)(vs + ch * 8);
            }
        }
        __syncthreads();

        // ---- QK: S[i][j], wave covers 64 i (4 frags) x its 16 j
        f32x4 sacc[4];
#pragma unroll
        for (int f = 0; f < 4; ++f) sacc[f] = f32x4{0.f, 0.f, 0.f, 0.f};
#pragma unroll
        for (int ks = 0; ks < 2; ++ks) {
            const int off = (ks * 64 + g * 16);
            const f16x8 B = *(const f16x8*)((char*)Qt + (wv * 16 + lm) * 128 + (off ^ key));
#pragma unroll
            for (int f = 0; f < 4; ++f) {
                const f16x8 A = *(const f16x8*)((char*)Kt + (f * 16 + lm) * 128 + (off ^ key));
                sacc[f] = __builtin_amdgcn_mfma_f32_16x16x32_f16(A, B, sacc[f], 0, 0, 0);
            }
        }

        // ---- online softmax (column j = j0 + wv*16 + lm, lane-local)
        float mt = -1e30f;
#pragma unroll
        for (int f = 0; f < 4; ++f)
#pragma unroll
            for (int e = 0; e < 4; ++e) mt = fmaxf(mt, sacc[f][e]);
        mt = fmaxf(mt, __shfl_xor(mt, 16));
        mt = fmaxf(mt, __shfl_xor(mt, 32));
        const float mnew = fmaxf(m, mt);
        const float rr = __expf(m - mnew);
        m = mnew;

        f16x4 p16[4];
        float zt = 0.f;
#pragma unroll
        for (int f = 0; f < 4; ++f) {
#pragma unroll
            for (int e = 0; e < 4; ++e) {
                const float ev = __expf(sacc[f][e] - mnew);
                zt += ev;
                p16[f][e] = (f16)ev;
            }
        }
        zt += __shfl_xor(zt, 16);
        zt += __shfl_xor(zt, 32);
        z = z * rr + zt;

#pragma unroll
        for (int cf = 0; cf < 4; ++cf) {
            accp[cf][0] *= rr; accp[cf][1] *= rr;
            accp[cf][2] *= rr; accp[cf][3] *= rr;
        }

        // ---- PV: att[c][j] += V[c][i-tile] * P
#pragma unroll
        for (int cf = 0; cf < 4; ++cf) {
#pragma unroll
            for (int f = 0; f < 4; ++f) {
                const f16x4 A = *(const f16x4*)((char*)Vt + (cf * 16 + lm) * 128 +
                                                ((f * 32 + g * 8) ^ key));
                accp[cf] = __builtin_amdgcn_mfma_f32_16x16x16f16(A, p16[f], accp[cf], 0, 0, 0);
            }
        }
    }

    // epilogue: attu[n][c][j] f16; Mcol/Zcol[n][j]
    const size_t abase = (size_t)n * CR;
    const int j = j0 + wv * 16 + lm;
#pragma unroll
    for (int cf = 0; cf < 4; ++cf)
#pragma unroll
        for (int e = 0; e < 4; ++e)
            attu[(abase + cf * 16 + g * 4 + e) * HW + j] = (f16)accp[cf][e];
    if (g == 0) {
        Mcol[(size_t)n * HW + j] = m;
        Zcol[(size_t)n * HW + j] = z;
    }
}

// ------------------------------------------------------------- global M, Z per n
__global__ __launch_bounds__(256) void reduce_kernel(
    const float* __restrict__ Mcol, const float* __restrict__ Zcol,
    float* __restrict__ Mn, float* __restrict__ Zn)
{
    const int n = blockIdx.x;
    const int tid = threadIdx.x;
    __shared__ float red[256];

    float lm = -1e30f;
    for (int j = tid; j < HW; j += 256) lm = fmaxf(lm, Mcol[(size_t)n * HW + j]);
    red[tid] = lm; __syncthreads();
    for (int s = 128; s > 0; s >>= 1) {
        if (tid < s) red[tid] = fmaxf(red[tid], red[tid + s]);
        __syncthreads();
    }
    const float M = red[0];
    __syncthreads();

    float ls = 0.f;
    for (int j = tid; j < HW; j += 256)
        ls += Zcol[(size_t)n * HW + j] * __expf(Mcol[(size_t)n * HW + j] - M);
    red[tid] = ls; __syncthreads();
    for (int s = 128; s > 0; s >>= 1) {
        if (tid < s) red[tid] += red[tid + s];
        __syncthreads();
    }
    if (tid == 0) { Mn[n] = M; Zn[n] = red[0]; }
}

// ------------------------- 1x1 conv + per-column scale + elementwise
__global__ __launch_bounds__(256) void final_kernel(
    const f16* __restrict__ attu, const float* __restrict__ Mcol,
    const float* __restrict__ Mn, const float* __restrict__ Zn,
    const float* __restrict__ watt, const float* __restrict__ batt,
    const float* __restrict__ gco, float* __restrict__ out)
{
    const int idx4 = blockIdx.x * 256 + threadIdx.x;
    const int p  = (idx4 % (HW / 4)) * 4;
    const int co = (idx4 / (HW / 4)) % CIN;
    const int n  = idx4 / ((HW / 4) * CIN);

    float t0[4] = {0.f, 0.f, 0.f, 0.f};
    const f16* a0 = attu + ((size_t)n * CR) * HW + p;
    const float* wa = watt + (size_t)co * CR;
#pragma unroll 8
    for (int c = 0; c < CR; ++c) {
        const f16x4 x0 = *(const f16x4*)(a0 + (size_t)c * HW);
        const float wv = wa[c];
#pragma unroll
        for (int e = 0; e < 4; ++e)
            t0[e] = fmaf(wv, (float)x0[e], t0[e]);
    }
    const float M = Mn[n];
    const float Zi = 1.f / Zn[n];
    const float4 mc0 = *(const float4*)(Mcol + (size_t)n * HW + p);
    const float bb = batt[co] + 1.f;
    const float4 gv = *(const float4*)(gco + (size_t)(n * CIN + co) * HW + p);
    float4 o;
    o.x = gv.x * (t0[0] * __expf(mc0.x - M) * Zi + bb);
    o.y = gv.y * (t0[1] * __expf(mc0.y - M) * Zi + bb);
    o.z = gv.z * (t0[2] * __expf(mc0.z - M) * Zi + bb);
    o.w = gv.w * (t0[3] * __expf(mc0.w - M) * Zi + bb);
    *(float4*)(out + (size_t)(n * CIN + co) * HW + p) = o;
}

// --------------------------------------------------------------------- launch
extern "C" void kernel_launch(void* const* d_in, const int* in_sizes, int n_in,
                              void* d_out, int out_size, void* d_ws, size_t ws_size,
                              hipStream_t stream)
{
    (void)in_sizes; (void)n_in; (void)out_size; (void)ws_size;
    const float* fm   = (const float*)d_in[0];
    const float* gco  = (const float*)d_in[1];
    const float* wq   = (const float*)d_in[2];
    const float* bq   = (const float*)d_in[3];
    const float* wk   = (const float*)d_in[4];
    const float* bk   = (const float*)d_in[5];
    const float* wv   = (const float*)d_in[6];
    const float* bv   = (const float*)d_in[7];
    const float* watt = (const float*)d_in[8];
    const float* batt = (const float*)d_in[9];
    float* out = (float*)d_out;

    // f16 scratch in d_out (28.8 MB of 33.5 MB): qT|kT|v|fmT. All dead before
    // final_kernel writes out (attn consumes qkv; convs consume fmT).
    f16* qT   = (f16*)out;            // [n][p][c]   4 MB
    f16* kT   = qT + QKV;             // [n][p][c]   4 MB
    f16* vvb  = kT + QKV;             // [n][c][p]   4 MB
    f16* fmT  = vvb + QKV;            // [n][p][ci]  16.8 MB

    // ws: wTq | wTk | wTv | attu | Mcol | Zcol | Mn | Zn  (7.18 MB, proven layout)
    unsigned char* wsb = (unsigned char*)d_ws;
    f16* wTq = (f16*)(wsb);                                   //  9*16384 f16
    f16* wTk = (f16*)(wsb + 294912);                          // 25*16384 f16
    f16* wTv = (f16*)(wsb + 1114112);                         // 49*16384 f16
    f16* attu = (f16*)(wsb + 2719744);                        // [n][c][j] f16, 4 MB
    float* Mcol = (float*)(wsb + 6914048);                    // [n][4096] f32
    float* Zcol = (float*)(wsb + 7045120);                    // [n][4096] f32
    float* Mn   = (float*)(wsb + 7176192);                    // 8 f32
    float* Zn   = (float*)(wsb + 7176224);                    // 8 f32

    prep_w<<<576, 256, 0, stream>>>(wq, wTq, 9);
    prep_w<<<1600, 256, 0, stream>>>(wk, wTk, 25);
    prep_w<<<3136, 256, 0, stream>>>(wv, wTv, 49);
    transpose_fm<<<NB * 64, 256, 0, stream>>>(fm, fmT);

    conv_mfma<3, 0><<<256, 512, 0, stream>>>(fmT, wTq, bq, qT);
    conv_mfma<5, 0><<<256, 512, 0, stream>>>(fmT, wTk, bk, kT);
    conv_mfma<7, 1><<<256, 512, 0, stream>>>(fmT, wTv, bv, vvb);

    attn_mfma<<<NB * 64, 256, 0, stream>>>(qT, kT, vvb, attu, Mcol, Zcol);
    reduce_kernel<<<NB, 256, 0, stream>>>(Mcol, Zcol, Mn, Zn);
    final_kernel<<<NB * CIN * HW / 1024, 256, 0, stream>>>(
        attu, Mcol, Mn, Zn, watt, batt, gco, out);
}

// Round 6
// 227.817 us; speedup vs baseline: 12.5143x; 1.2773x over previous
//
#include <hip/hip_runtime.h>
#include <math.h>

#define NB 8
#define CIN 256
#define CR 64
#define H 64
#define W 64
#define HW 4096

typedef _Float16 f16;
typedef _Float16 f16x8 __attribute__((ext_vector_type(8)));
typedef _Float16 f16x4 __attribute__((ext_vector_type(4)));
typedef float f32x4 __attribute__((ext_vector_type(4)));

static const size_t QKV = (size_t)NB * CR * HW;   // 2,097,152 elems per q/k/v buffer

// ------------------------------------------------------------- weight prep
// w[co][ci][dy][dx] fp32 -> wT[dy*K+dx][co][ci] fp16
__global__ __launch_bounds__(256) void prep_w(
    const float* __restrict__ src, f16* __restrict__ dst, int KK)
{
    int idx = blockIdx.x * 256 + threadIdx.x;    // < 64*256*KK
    int ci = idx & 255;
    int co = (idx >> 8) & 63;
    int off = idx >> 14;
    dst[((size_t)(off * 64 + co)) * 256 + ci] = (f16)src[((size_t)(co * 256 + ci)) * KK + off];
}

// ------------------------------------------------------- feature-map transpose
// fm f32 [n][ci][y][x] -> fmT f16 [n][y*64+x][ci]
__global__ __launch_bounds__(256) void transpose_fm(
    const float* __restrict__ fm, f16* __restrict__ fmT)
{
    const int y = blockIdx.x & 63;
    const int n = blockIdx.x >> 6;
    const int tid = threadIdx.x;
    __shared__ f16x4 tile[64 * 64];   // [x][slot], slot XOR-swizzled by x
    const int xw = tid & 63;
    const int wv = tid >> 6;
    const float* s0 = fm + ((size_t)n * CIN) * HW + y * W + xw;
#pragma unroll
    for (int cc = 0; cc < 16; ++cc) {
        const int slot = wv * 16 + cc;            // ci = slot*4 + e
        const float* s = s0 + (size_t)(slot * 4) * HW;
        f16x4 pk;
#pragma unroll
        for (int e = 0; e < 4; ++e) pk[e] = (f16)s[(size_t)e * HW];
        tile[xw * 64 + (slot ^ xw)] = pk;
    }
    __syncthreads();
    f16x4* dst = (f16x4*)fmT + ((size_t)n * HW + y * W) * 64;
#pragma unroll
    for (int it = 0; it < 16; ++it) {
        const int idx = tid + it * 256;           // < 4096
        const int x = idx >> 6;
        const int slot = idx & 63;
        dst[x * 64 + slot] = tile[x * 64 + (slot ^ x)];
    }
}

// ---------------------------------------------------------- MFMA conv K x K
// Grid 256 blocks (n, 2-row group), 512 threads = 8 waves (row r, co-half h, k-half sw).
// X from fmT (vectorized), W from wT; both XOR-swizzled 128B LDS rows.
// 2-way k-split accumulators merged through LDS at the end.
// LAYOUT 0: dst [n][p][c] f16 (q, k).  LAYOUT 1: dst [n][c][p] f16 (v).
template<int K, int LAYOUT>
__global__ __launch_bounds__(512) void conv_mfma(
    const f16* __restrict__ fmT, const f16* __restrict__ wT,
    const float* __restrict__ bias, f16* __restrict__ dst)
{
    constexpr int P = K / 2;
    constexpr int XBYTES = 2 * 72 * 128;          // 18432
    constexpr int WBYTES = K * 64 * 128;
    constexpr int TBYTES = XBYTES + WBYTES;
    constexpr int SBYTES = (TBYTES > 32768) ? TBYTES : 32768;
    __shared__ __align__(16) unsigned char smem[SBYTES];
    unsigned char* Xl = smem;
    unsigned char* Wl = smem + XBYTES;

    const int bid0 = blockIdx.x;
    const int bid = (bid0 & 7) * 32 + (bid0 >> 3);   // XCD swizzle, 256 = 8*32
    const int n  = bid >> 5;
    const int y0 = (bid & 31) * 2;
    const int tid = threadIdx.x;
    const int w = tid >> 6;
    const int lane = tid & 63;
    const int r  = w >> 2;        // row within block
    const int h  = (w >> 1) & 1;  // co half
    const int sw = w & 1;         // k half (32-ci sub-chunk)
    const int lm = lane & 15;
    const int g  = lane >> 4;

    // zero halo columns once (cols [0,P) and [64+P,72) of both slots)
    if (tid < 128) {
        const int sl = tid >> 6;
        const int cidx = (tid >> 3) & 7;
        const int chunk = tid & 7;
        const int col = (cidx < P) ? cidx : (64 + cidx);
        *(uint4*)(Xl + (size_t)(sl * 72 + col) * 128 + chunk * 16) = uint4{0, 0, 0, 0};
    }

    f32x4 acc[2][4];
#pragma unroll
    for (int i = 0; i < 2; ++i)
#pragma unroll
        for (int j = 0; j < 4; ++j) acc[i][j] = f32x4{0.f, 0.f, 0.f, 0.f};

    for (int dy = 0; dy < K; ++dy) {
        for (int ch = 0; ch < 4; ++ch) {
            __syncthreads();
            // ---- stage X: 2 rows x 64 x x 64 ci(ch) = 1024 uint4, 2/thread
#pragma unroll
            for (int p = 0; p < 2; ++p) {
                const int idx = tid + p * 512;
                const int sl = idx >> 9;
                const int x = (idx >> 3) & 63;
                const int chunk = idx & 7;
                const int iy = y0 + sl + dy - P;
                uint4 val = uint4{0, 0, 0, 0};
                if (iy >= 0 && iy < H)
                    val = *(const uint4*)(fmT + ((size_t)n * HW + iy * 64 + x) * 256 +
                                          ch * 64 + chunk * 8);
                *(uint4*)(Xl + (size_t)(sl * 72 + x + P) * 128 +
                          ((chunk * 16) ^ (((x + P) & 7) << 4))) = val;
            }
            // ---- stage W: K*512 uint4, K/thread
#pragma unroll
            for (int p = 0; p < K; ++p) {
                const int idx = tid + p * 512;
                const int cig = idx & 7;
                const int co  = (idx >> 3) & 63;
                const int dx  = idx >> 9;
                const f16* s = wT + ((size_t)((dy * K + dx) * 64 + co)) * 256 + ch * 64 + cig * 8;
                *(uint4*)(Wl + (size_t)(dx * 64 + co) * 128 +
                          ((cig * 16) ^ ((co & 7) << 4))) = *(const uint4*)s;
            }
            __syncthreads();
            // ---- compute: per wave dx(K) x 2cf x 4xf MFMA, one 32-ci k-half
#pragma unroll
            for (int dx = 0; dx < K; ++dx) {
                f16x8 a[2], b[4];
#pragma unroll
                for (int cf = 0; cf < 2; ++cf) {
                    const int co = h * 32 + cf * 16 + lm;
                    a[cf] = *(const f16x8*)(Wl + (size_t)(dx * 64 + co) * 128 +
                                            ((sw * 64 + g * 16) ^ ((co & 7) << 4)));
                }
#pragma unroll
                for (int xf = 0; xf < 4; ++xf) {
                    const int col = xf * 16 + lm + dx;
                    b[xf] = *(const f16x8*)(Xl + (size_t)(r * 72 + col) * 128 +
                                            ((sw * 64 + g * 16) ^ ((col & 7) << 4)));
                }
#pragma unroll
                for (int cf = 0; cf < 2; ++cf)
#pragma unroll
                    for (int xf = 0; xf < 4; ++xf)
                        acc[cf][xf] = __builtin_amdgcn_mfma_f32_16x16x32_f16(
                            a[cf], b[xf], acc[cf][xf], 0, 0, 0);
            }
        }
    }

    // ---- merge k-halves: sw=1 waves write acc, sw=0 waves add
    __syncthreads();
    {
        const int mslot = r * 2 + h;
        if (sw == 1) {
#pragma unroll
            for (int cf = 0; cf < 2; ++cf)
#pragma unroll
                for (int xf = 0; xf < 4; ++xf)
                    *(f32x4*)(smem + (size_t)(mslot * 64 + lane) * 128 +
                              (((cf * 4 + xf) * 16) ^ ((lane & 7) << 4))) = acc[cf][xf];
        }
        __syncthreads();
        if (sw == 0) {
#pragma unroll
            for (int cf = 0; cf < 2; ++cf)
#pragma unroll
                for (int xf = 0; xf < 4; ++xf)
                    acc[cf][xf] += *(const f32x4*)(smem + (size_t)(mslot * 64 + lane) * 128 +
                                                   (((cf * 4 + xf) * 16) ^ ((lane & 7) << 4)));
        }
    }

    // ---- epilogue (sw=0 waves): D col=lm -> x, row=g*4+reg -> co offset
    if (sw == 0) {
        const int y = y0 + r;
#pragma unroll
        for (int cf = 0; cf < 2; ++cf) {
            const float4 bv = *(const float4*)(bias + h * 32 + cf * 16 + g * 4);
            if (LAYOUT == 0) {
#pragma unroll
                for (int xf = 0; xf < 4; ++xf) {
                    f16x4 pk;
#pragma unroll
                    for (int e = 0; e < 4; ++e)
                        pk[e] = (f16)(acc[cf][xf][e] + ((const float*)&bv)[e]);
                    *(f16x4*)(dst + ((size_t)n * HW + y * W + xf * 16 + lm) * 64 +
                              h * 32 + cf * 16 + g * 4) = pk;
                }
            } else {
#pragma unroll
                for (int e = 0; e < 4; ++e) {
                    const int co = h * 32 + cf * 16 + g * 4 + e;
#pragma unroll
                    for (int xf = 0; xf < 4; ++xf)
                        dst[((size_t)(n * CR + co)) * HW + y * W + xf * 16 + lm] =
                            (f16)(acc[cf][xf][e] + ((const float*)&bv)[e]);
                }
            }
        }
    }
}

// ------------------------------------------------- fused MFMA attention
// block = (n, jt). 4 waves; wave w owns 16 columns j = jt*64 + w*16 + (lane&15),
// iterates all 4096 i in 64-i tiles. Softmax state (m,z) per column in registers.
// attu output layout: [n][j][c] f16 (contiguous c per spatial column).
__global__ __launch_bounds__(256, 2) void attn_mfma(
    const f16* __restrict__ qT, const f16* __restrict__ kT, const f16* __restrict__ vv,
    f16* __restrict__ attu, float* __restrict__ Mcol, float* __restrict__ Zcol)
{
    const int bid0 = blockIdx.x;
    const int bid = (bid0 & 7) * 64 + (bid0 >> 3);   // XCD swizzle, 512 = 8*64
    const int jt = bid & 63;
    const int n  = bid >> 6;
    const int j0 = jt * 64;
    const int tid = threadIdx.x;
    const int wv = tid >> 6;
    const int lane = tid & 63;
    const int lm = lane & 15;
    const int g  = lane >> 4;
    const int key = (lm & 7) << 4;

    __shared__ __align__(16) f16 Qt[64 * 64];
    __shared__ __align__(16) f16 Kt[64 * 64];
    __shared__ __align__(16) f16 Vt[64 * 64];

    // stage Qt once: qT[n][j0+j][c] -> rows [j][64c], XOR-swizzled 16B slots
    {
        const int r = tid >> 2;
        const f16* src = qT + ((size_t)n * HW + j0 + r) * 64;
#pragma unroll
        for (int h = 0; h < 2; ++h) {
            const int ch = (tid & 3) * 2 + h;
            *(uint4*)((char*)Qt + r * 128 + ((ch * 16) ^ ((r & 7) << 4))) =
                *(const uint4*)(src + ch * 8);
        }
    }

    float m = -1e30f, z = 0.f;
    f32x4 accp[4];
#pragma unroll
    for (int c = 0; c < 4; ++c) accp[c] = f32x4{0.f, 0.f, 0.f, 0.f};

    for (int it = 0; it < 64; ++it) {
        const int i0 = it * 64;
        __syncthreads();
        // stage Kt ([i][c]) and Vt ([c][i])
        {
            const int r = tid >> 2;
            const f16* ks = kT + ((size_t)n * HW + i0 + r) * 64;
            const f16* vs = vv + ((size_t)n * CR + r) * HW + i0;
#pragma unroll
            for (int h = 0; h < 2; ++h) {
                const int ch = (tid & 3) * 2 + h;
                *(uint4*)((char*)Kt + r * 128 + ((ch * 16) ^ ((r & 7) << 4))) =
                    *(const uint4*)(ks + ch * 8);
                *(uint4*)((char*)Vt + r * 128 + ((ch * 16) ^ ((r & 7) << 4))) =
                    *(const uint4*)(vs + ch * 8);
            }
        }
        __syncthreads();

        // ---- QK: S[i][j], wave covers 64 i (4 frags) x its 16 j
        f32x4 sacc[4];
#pragma unroll
        for (int f = 0; f < 4; ++f) sacc[f] = f32x4{0.f, 0.f, 0.f, 0.f};
#pragma unroll
        for (int ks = 0; ks < 2; ++ks) {
            const int off = (ks * 64 + g * 16);
            const f16x8 B = *(const f16x8*)((char*)Qt + (wv * 16 + lm) * 128 + (off ^ key));
#pragma unroll
            for (int f = 0; f < 4; ++f) {
                const f16x8 A = *(const f16x8*)((char*)Kt + (f * 16 + lm) * 128 + (off ^ key));
                sacc[f] = __builtin_amdgcn_mfma_f32_16x16x32_f16(A, B, sacc[f], 0, 0, 0);
            }
        }

        // ---- online softmax (column j = j0 + wv*16 + lm, lane-local)
        float mt = -1e30f;
#pragma unroll
        for (int f = 0; f < 4; ++f)
#pragma unroll
            for (int e = 0; e < 4; ++e) mt = fmaxf(mt, sacc[f][e]);
        mt = fmaxf(mt, __shfl_xor(mt, 16));
        mt = fmaxf(mt, __shfl_xor(mt, 32));
        const float mnew = fmaxf(m, mt);
        const float rr = __expf(m - mnew);
        m = mnew;

        f16x4 p16[4];
        float zt = 0.f;
#pragma unroll
        for (int f = 0; f < 4; ++f) {
#pragma unroll
            for (int e = 0; e < 4; ++e) {
                const float ev = __expf(sacc[f][e] - mnew);
                zt += ev;
                p16[f][e] = (f16)ev;
            }
        }
        zt += __shfl_xor(zt, 16);
        zt += __shfl_xor(zt, 32);
        z = z * rr + zt;

#pragma unroll
        for (int cf = 0; cf < 4; ++cf) {
            accp[cf][0] *= rr; accp[cf][1] *= rr;
            accp[cf][2] *= rr; accp[cf][3] *= rr;
        }

        // ---- PV: att[c][j] += V[c][i-tile] * P
#pragma unroll
        for (int cf = 0; cf < 4; ++cf) {
#pragma unroll
            for (int f = 0; f < 4; ++f) {
                const f16x4 A = *(const f16x4*)((char*)Vt + (cf * 16 + lm) * 128 +
                                                ((f * 32 + g * 8) ^ key));
                accp[cf] = __builtin_amdgcn_mfma_f32_16x16x16f16(A, p16[f], accp[cf], 0, 0, 0);
            }
        }
    }

    // epilogue: attu[n][j][c] f16 (contiguous f16x4 per cf); Mcol/Zcol[n][j]
    const int j = j0 + wv * 16 + lm;
    const size_t jbase = ((size_t)n * HW + j) * 64;
#pragma unroll
    for (int cf = 0; cf < 4; ++cf) {
        f16x4 pk;
#pragma unroll
        for (int e = 0; e < 4; ++e) pk[e] = (f16)accp[cf][e];
        *(f16x4*)(attu + jbase + cf * 16 + g * 4) = pk;
    }
    if (g == 0) {
        Mcol[(size_t)n * HW + j] = m;
        Zcol[(size_t)n * HW + j] = z;
    }
}

// ------------------------------------------------------------- global M, Z per n
__global__ __launch_bounds__(256) void reduce_kernel(
    const float* __restrict__ Mcol, const float* __restrict__ Zcol,
    float* __restrict__ Mn, float* __restrict__ Zn)
{
    const int n = blockIdx.x;
    const int tid = threadIdx.x;
    __shared__ float red[256];

    float lm = -1e30f;
    for (int j = tid; j < HW; j += 256) lm = fmaxf(lm, Mcol[(size_t)n * HW + j]);
    red[tid] = lm; __syncthreads();
    for (int s = 128; s > 0; s >>= 1) {
        if (tid < s) red[tid] = fmaxf(red[tid], red[tid + s]);
        __syncthreads();
    }
    const float M = red[0];
    __syncthreads();

    float ls = 0.f;
    for (int j = tid; j < HW; j += 256)
        ls += Zcol[(size_t)n * HW + j] * __expf(Mcol[(size_t)n * HW + j] - M);
    red[tid] = ls; __syncthreads();
    for (int s = 128; s > 0; s >>= 1) {
        if (tid < s) red[tid] += red[tid + s];
        __syncthreads();
    }
    if (tid == 0) { Mn[n] = M; Zn[n] = red[0]; }
}

// --------------------- MFMA 1x1 conv + per-column scale + elementwise
// block = (n, 128-p tile). 512 threads = 8 waves; wave w owns 32 co x 128 p.
// Wl: watt f16 [co][c] 32KB; Al: attu tile [p'][c] 16KB; both XOR-swizzled.
__global__ __launch_bounds__(512) void final_mfma(
    const f16* __restrict__ attu, const float* __restrict__ Mcol,
    const float* __restrict__ Mn, const float* __restrict__ Zn,
    const float* __restrict__ watt, const float* __restrict__ batt,
    const float* __restrict__ gco, float* __restrict__ out)
{
    __shared__ __align__(16) f16 Wl[256 * 64];   // 32 KB
    __shared__ __align__(16) f16 Al[128 * 64];   // 16 KB

    const int bid0 = blockIdx.x;
    const int bid = (bid0 & 7) * 32 + (bid0 >> 3);   // XCD swizzle: n == XCD
    const int n  = bid >> 5;
    const int p0 = (bid & 31) * 128;
    const int tid = threadIdx.x;
    const int wv = tid >> 6;
    const int lane = tid & 63;
    const int lm = lane & 15;
    const int g  = lane >> 4;

    // stage Wl: 256co x 64c f32 -> f16 (4096 float4, 8/thread)
#pragma unroll
    for (int t = 0; t < 8; ++t) {
        const int idx = tid + t * 512;
        const int co = idx >> 4;
        const int ch = idx & 15;
        const float4 w4 = *(const float4*)(watt + (size_t)co * 64 + ch * 4);
        f16x4 pk;
        pk[0] = (f16)w4.x; pk[1] = (f16)w4.y; pk[2] = (f16)w4.z; pk[3] = (f16)w4.w;
        *(f16x4*)((char*)Wl + co * 128 + ((ch * 8) ^ ((co & 7) << 4))) = pk;
    }
    // stage Al: 128p' x 64c f16 (2048 uint4, 4/thread)
#pragma unroll
    for (int t = 0; t < 4; ++t) {
        const int idx = tid + t * 512;
        const int pp = idx >> 3;
        const int ch = idx & 7;
        *(uint4*)((char*)Al + pp * 128 + ((ch * 16) ^ ((pp & 7) << 4))) =
            *(const uint4*)(attu + ((size_t)n * HW + p0 + pp) * 64 + ch * 8);
    }
    __syncthreads();

    f32x4 acc[2][8];
#pragma unroll
    for (int cf = 0; cf < 2; ++cf)
#pragma unroll
        for (int pf = 0; pf < 8; ++pf) acc[cf][pf] = f32x4{0.f, 0.f, 0.f, 0.f};

#pragma unroll
    for (int ks = 0; ks < 2; ++ks) {
        const int off = ks * 64 + g * 16;
        f16x8 A[2], B[8];
#pragma unroll
        for (int cf = 0; cf < 2; ++cf) {
            const int co = wv * 32 + cf * 16 + lm;
            A[cf] = *(const f16x8*)((char*)Wl + co * 128 + (off ^ ((co & 7) << 4)));
        }
#pragma unroll
        for (int pf = 0; pf < 8; ++pf) {
            const int pp = pf * 16 + lm;
            B[pf] = *(const f16x8*)((char*)Al + pp * 128 + (off ^ ((pp & 7) << 4)));
        }
#pragma unroll
        for (int cf = 0; cf < 2; ++cf)
#pragma unroll
            for (int pf = 0; pf < 8; ++pf)
                acc[cf][pf] = __builtin_amdgcn_mfma_f32_16x16x32_f16(
                    A[cf], B[pf], acc[cf][pf], 0, 0, 0);
    }

    const float M = Mn[n];
    const float Zi = 1.f / Zn[n];
    float ecol[8];
#pragma unroll
    for (int pf = 0; pf < 8; ++pf)
        ecol[pf] = __expf(Mcol[(size_t)n * HW + p0 + pf * 16 + lm] - M) * Zi;

    // D: col=lm -> p, row=g*4+e -> co offset
#pragma unroll
    for (int cf = 0; cf < 2; ++cf) {
#pragma unroll
        for (int e = 0; e < 4; ++e) {
            const int co = wv * 32 + cf * 16 + g * 4 + e;
            const float bb = batt[co] + 1.f;
            const float* gsrc = gco + (size_t)(n * CIN + co) * HW + p0 + lm;
            float* dstp = out + (size_t)(n * CIN + co) * HW + p0 + lm;
#pragma unroll
            for (int pf = 0; pf < 8; ++pf) {
                const float gvv = gsrc[pf * 16];
                dstp[pf * 16] = gvv * (acc[cf][pf][e] * ecol[pf] + bb);
            }
        }
    }
}

// --------------------------------------------------------------------- launch
extern "C" void kernel_launch(void* const* d_in, const int* in_sizes, int n_in,
                              void* d_out, int out_size, void* d_ws, size_t ws_size,
                              hipStream_t stream)
{
    (void)in_sizes; (void)n_in; (void)out_size; (void)ws_size;
    const float* fm   = (const float*)d_in[0];
    const float* gco  = (const float*)d_in[1];
    const float* wq   = (const float*)d_in[2];
    const float* bq   = (const float*)d_in[3];
    const float* wk   = (const float*)d_in[4];
    const float* bk   = (const float*)d_in[5];
    const float* wv   = (const float*)d_in[6];
    const float* bv   = (const float*)d_in[7];
    const float* watt = (const float*)d_in[8];
    const float* batt = (const float*)d_in[9];
    float* out = (float*)d_out;

    // f16 scratch in d_out (28.8 MB of 33.5 MB): qT|kT|v|fmT. All dead before
    // final_mfma writes out (attn consumes qkv; convs consume fmT).
    f16* qT   = (f16*)out;            // [n][p][c]   4 MB
    f16* kT   = qT + QKV;             // [n][p][c]   4 MB
    f16* vvb  = kT + QKV;             // [n][c][p]   4 MB
    f16* fmT  = vvb + QKV;            // [n][p][ci]  16.8 MB

    // ws: wTq | wTk | wTv | attu | Mcol | Zcol | Mn | Zn  (7.18 MB, proven layout)
    unsigned char* wsb = (unsigned char*)d_ws;
    f16* wTq = (f16*)(wsb);                                   //  9*16384 f16
    f16* wTk = (f16*)(wsb + 294912);                          // 25*16384 f16
    f16* wTv = (f16*)(wsb + 1114112);                         // 49*16384 f16
    f16* attu = (f16*)(wsb + 2719744);                        // [n][p][c] f16, 4 MB
    float* Mcol = (float*)(wsb + 6914048);                    // [n][4096] f32
    float* Zcol = (float*)(wsb + 7045120);                    // [n][4096] f32
    float* Mn   = (float*)(wsb + 7176192);                    // 8 f32
    float* Zn   = (float*)(wsb + 7176224);                    // 8 f32

    prep_w<<<576, 256, 0, stream>>>(wq, wTq, 9);
    prep_w<<<1600, 256, 0, stream>>>(wk, wTk, 25);
    prep_w<<<3136, 256, 0, stream>>>(wv, wTv, 49);
    transpose_fm<<<NB * 64, 256, 0, stream>>>(fm, fmT);

    conv_mfma<3, 0><<<256, 512, 0, stream>>>(fmT, wTq, bq, qT);
    conv_mfma<5, 0><<<256, 512, 0, stream>>>(fmT, wTk, bk, kT);
    conv_mfma<7, 1><<<256, 512, 0, stream>>>(fmT, wTv, bv, vvb);

    attn_mfma<<<NB * 64, 256, 0, stream>>>(qT, kT, vvb, attu, Mcol, Zcol);
    reduce_kernel<<<NB, 256, 0, stream>>>(Mcol, Zcol, Mn, Zn);
    final_mfma<<<256, 512, 0, stream>>>(attu, Mcol, Mn, Zn, watt, batt, gco, out);
}